// Round 4
// baseline (126435.730 us; speedup 1.0000x reference)
//
#include <hip/hip_runtime.h>
#include <hip/hip_fp16.h>
#include <math.h>

#define HH 512
#define BB 128
#define SS 1024
#define TT 128
#define VV 32
#define GG 1536

#define ENC_BLOCKS 384
#define DEC_BLOCKS 256

__device__ __forceinline__ float sigm(float v){ return 1.f/(1.f+expf(-v)); }
__device__ __forceinline__ float fast_tanh(float x){
  float ax = fabsf(x);
  float t = expf(-2.f*ax);
  float r = (1.f - t)/(1.f + t);
  return copysignf(r, x);
}

struct F8 { float v[8]; };

__device__ __forceinline__ F8 load8(const float* p){
  F8 r;
  float4 a = *reinterpret_cast<const float4*>(p);
  float4 b = *reinterpret_cast<const float4*>(p+4);
  r.v[0]=a.x; r.v[1]=a.y; r.v[2]=a.z; r.v[3]=a.w;
  r.v[4]=b.x; r.v[5]=b.y; r.v[6]=b.z; r.v[7]=b.w;
  return r;
}
__device__ __forceinline__ F8 load8(const __half* p){
  F8 r;
  union { float4 f4; __half2 h2[4]; } u;
  u.f4 = *reinterpret_cast<const float4*>(p);
  #pragma unroll
  for (int i=0;i<4;i++){ float2 f = __half22float2(u.h2[i]); r.v[2*i]=f.x; r.v[2*i+1]=f.y; }
  return r;
}
__device__ __forceinline__ void store_enc(float* p, float v){ *p = v; }
__device__ __forceinline__ void store_enc(__half* p, float v){ *p = __float2half(v); }

// grid-wide barrier: monotonic counter in global mem; agent fences for
// cross-XCD visibility (release: wb L2; acquire: inv L1/L2).
__device__ __forceinline__ void grid_bar(unsigned* bar, unsigned target){
  __syncthreads();                     // all waves drain their stores (waitcnt before s_barrier)
  if (threadIdx.x == 0) {
    __threadfence();                   // agent release
    atomicAdd(bar, 1u);
    while (__hip_atomic_load(bar, __ATOMIC_RELAXED, __HIP_MEMORY_SCOPE_AGENT) < target)
      __builtin_amdgcn_s_sleep(1);
    __threadfence();                   // agent acquire
  }
  __syncthreads();
}

// ---------- transpose (Wc only) ----------
__global__ void transpose_k(const float* __restrict__ src, float* __restrict__ dst,
                            int R, int C){
  __shared__ float tile[32][33];
  int c0 = blockIdx.x*32, r0 = blockIdx.y*32;
  int tx = threadIdx.x & 31, ty = threadIdx.x >> 5;
  for (int i = ty; i < 32; i += 8){
    int r = r0 + i, c = c0 + tx;
    tile[i][tx] = (r < R && c < C) ? src[(size_t)r*C + c] : 0.f;
  }
  __syncthreads();
  for (int i = ty; i < 32; i += 8){
    int c = c0 + i, r = r0 + tx;
    if (c < C && r < R) dst[(size_t)c*R + r] = tile[tx][i];
  }
}

// ---------- k-panel pack: W[R][512] -> P[(k>>2)*R*4 + r*4 + (k&3)] ----------
__global__ void pack_w(const float* __restrict__ src, float* __restrict__ dst, int R){
  int idx = blockIdx.x*256 + threadIdx.x;
  int r = idx >> 9, k = idx & 511;
  dst[((size_t)(k>>2)*R + r)*4 + (k&3)] = src[idx];
}

// ---------- dot: 8 batches x 1 row over k=512; weights packed, h in LDS ----------
__device__ __forceinline__ void dot8(const float4* __restrict__ wp, int row, int NR,
                                     const float4* sh4, float acc[8]){
  float4 wc = wp[row];
  for (int kc = 0; kc < 128; kc++) {
    float4 wn = wp[(size_t)(kc+1)*NR + row];   // slack-padded
    #pragma unroll
    for (int i = 0; i < 8; i++) {
      float4 h4 = sh4[i*128 + kc];
      acc[i] = fmaf(wc.w, h4.w, fmaf(wc.z, h4.z, fmaf(wc.y, h4.y, fmaf(wc.x, h4.x, acc[i]))));
    }
    wc = wn;
  }
}

// ================= persistent encoder =================
struct EncArgs {
  const float *x, *Wih0, *bih0, *bhh0, *bih1, *bhh1;
  const float *Whh0P, *Wih1P, *Whh1P;
  float *gh_all, *h0buf, *h1buf;
  void *out_enc;
  unsigned *bar;
};

template<typename ET>
__global__ __launch_bounds__(192) void enc_persist(EncArgs A)
{
  __shared__ float4 sh4[1024];                  // 16 KB
  float* shs = (float*)sh4;
  const int bid = blockIdx.x;
  const int xcd = bid & 7, j = bid >> 3;        // j in [0,48)
  const int rc  = xcd*3 + (j % 3);              // [0,24)  XCD-pinned rowchunks
  const int bch = j / 3;                        // [0,16)
  const int m   = rc >> 3;                      // 0..2
  const int b0  = bch*8;
  const int tid = threadIdx.x;
  ET* out_enc = (ET*)A.out_enc;

  for (int p = 0; p <= SS; ++p) {
    const int pb = p & 1;
    const bool active = !((m == 0 && p >= SS) || (m >= 1 && p < 1));
    if (active) {
      if (m <= 1) {
        float* h0w = A.h0buf + (size_t)pb*BB*HH;
        for (int idx = tid; idx < 8*HH; idx += 192) {
          int bl = idx >> 9, e = idx & (HH-1);
          int b = b0 + bl;
          float hv;
          if (p == 0) hv = 0.f;
          else {
            int t0 = p - 1;
            float x0v = A.x[((size_t)b*SS + t0)*2 + 0];
            float x1v = A.x[((size_t)b*SS + t0)*2 + 1];
            const float* ghp = A.gh_all + ((size_t)(1-pb)*3 + 0)*BB*GG + (size_t)b*GG;
            float gir = fmaf(x0v, A.Wih0[e*2],        fmaf(x1v, A.Wih0[e*2+1],        A.bih0[e]));
            float giz = fmaf(x0v, A.Wih0[(HH+e)*2],   fmaf(x1v, A.Wih0[(HH+e)*2+1],   A.bih0[HH+e]));
            float gin = fmaf(x0v, A.Wih0[(2*HH+e)*2], fmaf(x1v, A.Wih0[(2*HH+e)*2+1], A.bih0[2*HH+e]));
            float ghr = ghp[e]      + A.bhh0[e];
            float ghz = ghp[HH+e]   + A.bhh0[HH+e];
            float ghn = ghp[2*HH+e] + A.bhh0[2*HH+e];
            float hp = (p == 1) ? 0.f : A.h0buf[(size_t)(1-pb)*BB*HH + (size_t)b*HH + e];
            float r = sigm(gir + ghr);
            float z = sigm(giz + ghz);
            float n = fast_tanh(fmaf(r, ghn, gin));
            hv = (1.f - z)*n + z*hp;
          }
          h0w[(size_t)b*HH + e] = hv;
          shs[idx] = hv;
        }
      } else {
        float* h1w = A.h1buf + (size_t)pb*BB*HH;
        for (int idx = tid; idx < 8*HH; idx += 192) {
          int bl = idx >> 9, e = idx & (HH-1);
          int b = b0 + bl;
          float hv;
          if (p <= 1) hv = 0.f;
          else {
            const float* gip = A.gh_all + ((size_t)(1-pb)*3 + 1)*BB*GG + (size_t)b*GG;
            const float* ghp = A.gh_all + ((size_t)(1-pb)*3 + 2)*BB*GG + (size_t)b*GG;
            float gir = gip[e]      + A.bih1[e];
            float giz = gip[HH+e]   + A.bih1[HH+e];
            float gin = gip[2*HH+e] + A.bih1[2*HH+e];
            float ghr = ghp[e]      + A.bhh1[e];
            float ghz = ghp[HH+e]   + A.bhh1[HH+e];
            float ghn = ghp[2*HH+e] + A.bhh1[2*HH+e];
            float hp = (p == 2) ? 0.f : A.h1buf[(size_t)(1-pb)*BB*HH + (size_t)b*HH + e];
            float r = sigm(gir + ghr);
            float z = sigm(giz + ghz);
            float n = fast_tanh(fmaf(r, ghn, gin));
            hv = (1.f - z)*n + z*hp;
          }
          h1w[(size_t)b*HH + e] = hv;
          shs[idx] = hv;
          if (p >= 2) store_enc(out_enc + ((size_t)b*SS + (p-2))*HH + e, hv);
        }
      }
      __syncthreads();

      const float4* WP = (const float4*)((m == 0) ? A.Whh0P : (m == 1) ? A.Wih1P : A.Whh1P);
      const int wv = tid >> 6, lane = tid & 63;
      const int row = (rc & 7)*192 + wv*64 + lane;
      float acc[8] = {0,0,0,0,0,0,0,0};
      dot8(WP, row, GG, sh4, acc);
      float* dst = A.gh_all + ((size_t)pb*3 + m)*BB*GG;
      #pragma unroll
      for (int i = 0; i < 8; i++) dst[(size_t)(b0+i)*GG + row] = acc[i];
    }
    grid_bar(A.bar, (unsigned)(p+1) * (unsigned)ENC_BLOCKS);
  }
}

// ---------- bridge: finalize h1[1023] ----------
template<typename ET>
__global__ void enc_bridge(
    const float* __restrict__ gh_all, const float* __restrict__ h1buf,
    const float* __restrict__ bih1, const float* __restrict__ bhh1,
    float* __restrict__ h1init, ET* __restrict__ out_enc)
{
  int idx = blockIdx.x*256 + threadIdx.x;
  int b = idx >> 9, e = idx & (HH-1);
  const float* gip = gh_all + (size_t)1*BB*GG + (size_t)b*GG;
  const float* ghp = gh_all + (size_t)2*BB*GG + (size_t)b*GG;
  float gir = gip[e]      + bih1[e];
  float giz = gip[HH+e]   + bih1[HH+e];
  float gin = gip[2*HH+e] + bih1[2*HH+e];
  float ghr = ghp[e]      + bhh1[e];
  float ghz = ghp[HH+e]   + bhh1[HH+e];
  float ghn = ghp[2*HH+e] + bhh1[2*HH+e];
  float hp = h1buf[(size_t)b*HH + e];
  float r = sigm(gir + ghr);
  float z = sigm(giz + ghz);
  float n = fast_tanh(fmaf(r, ghn, gin));
  float hv = (1.f - z)*n + z*hp;
  h1init[(size_t)b*HH + e] = hv;
  store_enc(out_enc + ((size_t)b*SS + (SS-1))*HH + e, hv);
}

// ================= persistent decoder =================
struct DecArgs {
  const float *emb;
  const float *bih0d, *bhh0d, *bih1d, *bhh1d, *bq, *bc;
  const float *Wih0P, *Whh0P, *Wih1P, *Whh1P, *WqP, *WcT;
  const float *h0init, *h1init;
  float *dgh0, *dgh1, *h0d, *h1d, *h0n, *h1n, *qbuf;
  float *att, *pm, *pl, *pctx;
  int *tok;
  void *out_enc;
  float *out_vec, *out_attn, *out_hid;
  unsigned *bar;
};

template<typename ET>
__global__ __launch_bounds__(256) void dec_persist(DecArgs A)
{
  __shared__ float4 smem4[1024];                // 16 KB, reused per phase
  float* smem = (float*)smem4;
  __shared__ float lm[4], ll[4];
  __shared__ float s_red[8][33];
  const int bid = blockIdx.x;
  const int tid = threadIdx.x;
  const int wv = tid >> 6, lane = tid & 63;
  ET* out_enc = (ET*)A.out_enc;
  unsigned gens = 0;

  for (int t = 0; t < TT; ++t) {
    const int db = t & 1;

    // ---- phase A: cell0 dots (192 units: m(2) x rowu(6) x bch(16)) ----
    if (bid < 192) {
      const int m = bid / 96, v = bid % 96, rowu = v / 16, bch = v % 16, b0 = bch*8;
      if (m == 1) {
        for (int idx = tid; idx < 8*HH; idx += 256) {
          int bl = idx >> 9, e = idx & (HH-1);
          int b = b0 + bl;
          float hv;
          if (t == 0) hv = A.h0init[(size_t)b*HH + e];
          else {
            const float* gip = A.dgh0 + ((size_t)(1-db)*2 + 0)*BB*GG + (size_t)b*GG;
            const float* ghp = A.dgh0 + ((size_t)(1-db)*2 + 1)*BB*GG + (size_t)b*GG;
            float gir = gip[e]      + A.bih0d[e];
            float giz = gip[HH+e]   + A.bih0d[HH+e];
            float gin = gip[2*HH+e] + A.bih0d[2*HH+e];
            float ghr = ghp[e]      + A.bhh0d[e];
            float ghz = ghp[HH+e]   + A.bhh0d[HH+e];
            float ghn = ghp[2*HH+e] + A.bhh0d[2*HH+e];
            float hp = (t == 1) ? A.h0init[(size_t)b*HH + e]
                                : A.h0d[(size_t)(1-db)*BB*HH + (size_t)b*HH + e];
            float r = sigm(gir + ghr);
            float z = sigm(giz + ghz);
            float n = fast_tanh(fmaf(r, ghn, gin));
            hv = (1.f - z)*n + z*hp;
          }
          smem[idx] = hv;
          if (rowu == 0) A.h0d[(size_t)db*BB*HH + (size_t)b*HH + e] = hv;
        }
      } else {
        for (int idx = tid; idx < 8*HH; idx += 256) {
          int bl = idx >> 9, e = idx & (HH-1);
          int tk = A.tok[b0 + bl];
          smem[idx] = A.emb[(size_t)tk*HH + e];
        }
      }
      __syncthreads();
      const float4* WP = (const float4*)((m == 0) ? A.Wih0P : A.Whh0P);
      const int row = rowu*256 + tid;
      float acc[8] = {0,0,0,0,0,0,0,0};
      dot8(WP, row, GG, smem4, acc);
      float* dst = A.dgh0 + ((size_t)db*2 + m)*BB*GG;
      #pragma unroll
      for (int i = 0; i < 8; i++) dst[(size_t)(b0+i)*GG + row] = acc[i];
    }
    grid_bar(A.bar, (++gens) * (unsigned)DEC_BLOCKS);

    // ---- phase B: cell1 dots (192 units) ----
    if (bid < 192) {
      const int m = bid / 96, v = bid % 96, rowu = v / 16, bch = v % 16, b0 = bch*8;
      if (m == 0) {
        for (int idx = tid; idx < 8*HH; idx += 256) {
          int bl = idx >> 9, e = idx & (HH-1);
          int b = b0 + bl;
          const float* gip = A.dgh0 + ((size_t)db*2 + 0)*BB*GG + (size_t)b*GG;
          const float* ghp = A.dgh0 + ((size_t)db*2 + 1)*BB*GG + (size_t)b*GG;
          float gir = gip[e]      + A.bih0d[e];
          float giz = gip[HH+e]   + A.bih0d[HH+e];
          float gin = gip[2*HH+e] + A.bih0d[2*HH+e];
          float ghr = ghp[e]      + A.bhh0d[e];
          float ghz = ghp[HH+e]   + A.bhh0d[HH+e];
          float ghn = ghp[2*HH+e] + A.bhh0d[2*HH+e];
          float hp = A.h0d[(size_t)db*BB*HH + (size_t)b*HH + e];
          float r = sigm(gir + ghr);
          float z = sigm(giz + ghz);
          float n = fast_tanh(fmaf(r, ghn, gin));
          float hv = (1.f - z)*n + z*hp;
          smem[idx] = hv;
          if (rowu == 0) A.h0n[(size_t)b*HH + e] = hv;
        }
      } else {
        for (int idx = tid; idx < 8*HH; idx += 256) {
          int bl = idx >> 9, e = idx & (HH-1);
          int b = b0 + bl;
          float hv;
          if (t == 0) hv = A.h1init[(size_t)b*HH + e];
          else {
            const float* gip = A.dgh1 + ((size_t)(1-db)*2 + 0)*BB*GG + (size_t)b*GG;
            const float* ghp = A.dgh1 + ((size_t)(1-db)*2 + 1)*BB*GG + (size_t)b*GG;
            float gir = gip[e]      + A.bih1d[e];
            float giz = gip[HH+e]   + A.bih1d[HH+e];
            float gin = gip[2*HH+e] + A.bih1d[2*HH+e];
            float ghr = ghp[e]      + A.bhh1d[e];
            float ghz = ghp[HH+e]   + A.bhh1d[HH+e];
            float ghn = ghp[2*HH+e] + A.bhh1d[2*HH+e];
            float hp = (t == 1) ? A.h1init[(size_t)b*HH + e]
                                : A.h1d[(size_t)(1-db)*BB*HH + (size_t)b*HH + e];
            float r = sigm(gir + ghr);
            float z = sigm(giz + ghz);
            float n = fast_tanh(fmaf(r, ghn, gin));
            hv = (1.f - z)*n + z*hp;
          }
          smem[idx] = hv;
          if (rowu == 0) A.h1d[(size_t)db*BB*HH + (size_t)b*HH + e] = hv;
        }
      }
      __syncthreads();
      const float4* WP = (const float4*)((m == 0) ? A.Wih1P : A.Whh1P);
      const int row = rowu*256 + tid;
      float acc[8] = {0,0,0,0,0,0,0,0};
      dot8(WP, row, GG, smem4, acc);
      float* dst = A.dgh1 + ((size_t)db*2 + m)*BB*GG;
      #pragma unroll
      for (int i = 0; i < 8; i++) dst[(size_t)(b0+i)*GG + row] = acc[i];
    }
    grid_bar(A.bar, (++gens) * (unsigned)DEC_BLOCKS);

    // ---- phase C: h1n + q (32 units: rowu(2) x bch(16)) ----
    if (bid < 32) {
      const int rowu = bid & 1, bch = bid >> 1, b0 = bch*8;
      for (int idx = tid; idx < 8*HH; idx += 256) {
        int bl = idx >> 9, e = idx & (HH-1);
        int b = b0 + bl;
        const float* gip = A.dgh1 + ((size_t)db*2 + 0)*BB*GG + (size_t)b*GG;
        const float* ghp = A.dgh1 + ((size_t)db*2 + 1)*BB*GG + (size_t)b*GG;
        float gir = gip[e]      + A.bih1d[e];
        float giz = gip[HH+e]   + A.bih1d[HH+e];
        float gin = gip[2*HH+e] + A.bih1d[2*HH+e];
        float ghr = ghp[e]      + A.bhh1d[e];
        float ghz = ghp[HH+e]   + A.bhh1d[HH+e];
        float ghn = ghp[2*HH+e] + A.bhh1d[2*HH+e];
        float hp = A.h1d[(size_t)db*BB*HH + (size_t)b*HH + e];
        float r = sigm(gir + ghr);
        float z = sigm(giz + ghz);
        float n = fast_tanh(fmaf(r, ghn, gin));
        float hv = (1.f - z)*n + z*hp;
        smem[idx] = hv;
        if (rowu == 0) A.h1n[(size_t)b*HH + e] = hv;
      }
      __syncthreads();
      const int row = rowu*256 + tid;
      float acc[8] = {0,0,0,0,0,0,0,0};
      dot8((const float4*)A.WqP, row, HH, smem4, acc);
      #pragma unroll
      for (int i = 0; i < 8; i++) A.qbuf[(size_t)(b0+i)*HH + row] = acc[i] + A.bq[row];
    }
    grid_bar(A.bar, (++gens) * (unsigned)DEC_BLOCKS);

    // ---- phase D: attention (1024 units, 4 per block) ----
    for (int u = bid; u < BB*8; u += DEC_BLOCKS) {
      const int b = u >> 3, sc = u & 7;
      __syncthreads();                           // protect smem reuse
      const F8 q = load8(A.qbuf + (size_t)b*HH + lane*8);
      const ET* encb = out_enc + (size_t)b*SS*HH;
      float mrun = -1e30f, lrun = 0.f;
      float c[8] = {0,0,0,0,0,0,0,0};
      float attkeep = 0.f;
      const int sbase = sc*128 + wv*32;
      for (int ii = 0; ii < 32; ii++) {
        const F8 e = load8(encb + (size_t)(sbase + ii)*HH + lane*8);
        float d = 0.f;
        #pragma unroll
        for (int jj = 0; jj < 8; jj++) d = fmaf(q.v[jj], e.v[jj], d);
        #pragma unroll
        for (int off = 32; off >= 1; off >>= 1) d += __shfl_xor(d, off, 64);
        if (lane == ii) attkeep = d;
        float mnew = fmaxf(mrun, d);
        float scal = expf(mrun - mnew);
        float pv = expf(d - mnew);
        lrun = fmaf(lrun, scal, pv);
        #pragma unroll
        for (int jj = 0; jj < 8; jj++) c[jj] = fmaf(c[jj], scal, pv*e.v[jj]);
        mrun = mnew;
      }
      if (lane < 32) A.att[(size_t)b*SS + sbase + lane] = attkeep;
      if (lane == 0) { lm[wv] = mrun; ll[wv] = lrun; }
      #pragma unroll
      for (int jj = 0; jj < 8; jj++) smem[wv*HH + lane*8 + jj] = c[jj];
      __syncthreads();
      float mb = fmaxf(fmaxf(lm[0],lm[1]), fmaxf(lm[2],lm[3]));
      float e0w = expf(lm[0]-mb), e1w = expf(lm[1]-mb), e2w = expf(lm[2]-mb), e3w = expf(lm[3]-mb);
      if (tid == 0) {
        A.pm[b*8+sc] = mb;
        A.pl[b*8+sc] = e0w*ll[0] + e1w*ll[1] + e2w*ll[2] + e3w*ll[3];
      }
      for (int k2 = tid; k2 < HH; k2 += 256) {
        float s = e0w*smem[0*HH+k2] + e1w*smem[1*HH+k2] + e2w*smem[2*HH+k2] + e3w*smem[3*HH+k2];
        A.pctx[((size_t)b*8 + sc)*HH + k2] = s;
      }
    }
    grid_bar(A.bar, (++gens) * (unsigned)DEC_BLOCKS);

    // ---- phase E: combine + attn-out + logits + argmax (128 units) ----
    if (bid < BB) {
      const int b = bid;
      float* s_hc = smem;                        // 2*HH floats
      float pmv[8], plv[8];
      #pragma unroll
      for (int c8 = 0; c8 < 8; c8++){ pmv[c8] = A.pm[b*8+c8]; plv[c8] = A.pl[b*8+c8]; }
      float mg = pmv[0];
      #pragma unroll
      for (int c8 = 1; c8 < 8; c8++) mg = fmaxf(mg, pmv[c8]);
      float epm[8]; float lg = 0.f;
      #pragma unroll
      for (int c8 = 0; c8 < 8; c8++){ epm[c8] = expf(pmv[c8]-mg); lg += epm[c8]*plv[c8]; }
      float inv_lg = 1.f/lg;
      for (int k = tid; k < HH; k += 256) {
        float s = 0.f;
        #pragma unroll
        for (int c8 = 0; c8 < 8; c8++) s += epm[c8]*A.pctx[((size_t)b*8+c8)*HH + k];
        s_hc[HH + k] = s * inv_lg;
        s_hc[k] = A.h1n[(size_t)b*HH + k];
      }
      __syncthreads();
      for (int s = tid; s < SS; s += 256)
        A.out_attn[((size_t)b*SS + s)*TT + t] = expf(A.att[(size_t)b*SS + s] - mg) * inv_lg;
      const int v = tid & 31, part = tid >> 5;
      float pacc = 0.f;
      for (int k = part*128; k < part*128 + 128; k++)
        pacc = fmaf(s_hc[k], A.WcT[(size_t)k*VV + v], pacc);
      s_red[part][v] = pacc;
      __syncthreads();
      if (tid < 32) {
        float lv = A.bc[tid];
        #pragma unroll
        for (int c8 = 0; c8 < 8; c8++) lv += s_red[c8][tid];
        A.out_vec[((size_t)b*TT + t)*VV + tid] = lv;
        float bv = lv; int bi = tid;
        #pragma unroll
        for (int off = 16; off >= 1; off >>= 1) {
          float ov = __shfl_xor(bv, off, 64);
          int   oi = __shfl_xor(bi, off, 64);
          if (ov > bv || (ov == bv && oi < bi)) { bv = ov; bi = oi; }
        }
        if (tid == 0) A.tok[b] = bi;
      }
    }
    grid_bar(A.bar, (++gens) * (unsigned)DEC_BLOCKS);
  }

  // ---- final hidden-state output ----
  for (int i = bid*256 + tid; i < BB*HH; i += DEC_BLOCKS*256) {
    A.out_hid[i] = A.h0n[i];
    A.out_hid[BB*HH + i] = A.h1n[i];
  }
}

// ================= host =================
template<typename ET>
static void launch_all(EncArgs& EA, DecArgs& DA, hipStream_t stream) {
  void* ep[1] = { &EA };
  hipLaunchCooperativeKernel((const void*)&enc_persist<ET>, dim3(ENC_BLOCKS), dim3(192),
                             ep, 0, stream);
  enc_bridge<ET><<<dim3(256), dim3(256), 0, stream>>>(
      EA.gh_all, EA.h1buf, EA.bih1, EA.bhh1,
      (float*)DA.h1init, (ET*)EA.out_enc);
  void* dp[1] = { &DA };
  hipLaunchCooperativeKernel((const void*)&dec_persist<ET>, dim3(DEC_BLOCKS), dim3(256),
                             dp, 0, stream);
}

extern "C" void kernel_launch(void* const* d_in, const int* in_sizes, int n_in,
                              void* d_out, int out_size, void* d_ws, size_t ws_size,
                              hipStream_t stream) {
  const float* x      = (const float*)d_in[0];
  const float* emb    = (const float*)d_in[1];
  const float* eWih0  = (const float*)d_in[2];
  const float* eWhh0  = (const float*)d_in[3];
  const float* ebih0  = (const float*)d_in[4];
  const float* ebhh0  = (const float*)d_in[5];
  const float* eWih1  = (const float*)d_in[6];
  const float* eWhh1  = (const float*)d_in[7];
  const float* ebih1  = (const float*)d_in[8];
  const float* ebhh1  = (const float*)d_in[9];
  const float* dWih0  = (const float*)d_in[10];
  const float* dWhh0  = (const float*)d_in[11];
  const float* dbih0  = (const float*)d_in[12];
  const float* dbhh0  = (const float*)d_in[13];
  const float* dWih1  = (const float*)d_in[14];
  const float* dWhh1  = (const float*)d_in[15];
  const float* dbih1  = (const float*)d_in[16];
  const float* dbhh1  = (const float*)d_in[17];
  const float* Wq     = (const float*)d_in[18];
  const float* bq     = (const float*)d_in[19];
  const float* Wc     = (const float*)d_in[20];
  const float* bc     = (const float*)d_in[21];
  (void)in_sizes; (void)n_in; (void)out_size;

  float* ws = (float*)d_ws;
  size_t off = 0;
  auto alloc = [&](size_t n){ float* p = ws + off; off += n; return p; };
  const size_t PKB = (size_t)GG*HH + 4*GG;
  const size_t PKQ = (size_t)HH*HH + 4*HH;

  float* gh_all  = alloc((size_t)2*3*BB*GG);
  float* dgh0    = alloc((size_t)2*2*BB*GG);
  float* dgh1    = alloc((size_t)2*2*BB*GG);
  float* h0buf   = alloc((size_t)2*BB*HH);
  float* h1buf   = alloc((size_t)2*BB*HH);
  float* h0d     = alloc((size_t)2*BB*HH);
  float* h1d     = alloc((size_t)2*BB*HH);
  float* h0n     = alloc((size_t)BB*HH);
  float* h1n     = alloc((size_t)BB*HH);
  float* h1init  = alloc((size_t)BB*HH);
  float* qbuf    = alloc((size_t)BB*HH);
  float* att     = alloc((size_t)BB*SS);
  float* pmb     = alloc((size_t)BB*8);
  float* plb     = alloc((size_t)BB*8);
  float* pctx    = alloc((size_t)BB*8*HH);
  int*   tok     = (int*)alloc((size_t)BB);
  float* barbuf  = alloc((size_t)64);
  float* Whh0P   = alloc(PKB);
  float* Wih1P   = alloc(PKB);
  float* Whh1P   = alloc(PKB);
  float* dWih0P  = alloc(PKB);
  float* dWhh0P  = alloc(PKB);
  float* dWih1P  = alloc(PKB);
  float* dWhh1P  = alloc(PKB);
  float* WqP     = alloc(PKQ);
  float* WcT     = alloc((size_t)2*HH*VV);

  float* out_vec  = (float*)d_out;
  float* out_hid  = (float*)d_out + (size_t)BB*TT*VV;
  float* out_attn = (float*)d_out + (size_t)BB*TT*VV + (size_t)2*BB*HH;

  hipMemsetAsync(barbuf, 0, 64*sizeof(float), stream);
  hipMemsetAsync(tok, 0, BB*sizeof(int), stream);

  dim3 tb(256);
  pack_w<<<dim3(GG*HH/256), tb, 0, stream>>>(eWhh0, Whh0P, GG);
  pack_w<<<dim3(GG*HH/256), tb, 0, stream>>>(eWih1, Wih1P, GG);
  pack_w<<<dim3(GG*HH/256), tb, 0, stream>>>(eWhh1, Whh1P, GG);
  pack_w<<<dim3(GG*HH/256), tb, 0, stream>>>(dWih0, dWih0P, GG);
  pack_w<<<dim3(GG*HH/256), tb, 0, stream>>>(dWhh0, dWhh0P, GG);
  pack_w<<<dim3(GG*HH/256), tb, 0, stream>>>(dWih1, dWih1P, GG);
  pack_w<<<dim3(GG*HH/256), tb, 0, stream>>>(dWhh1, dWhh1P, GG);
  pack_w<<<dim3(HH*HH/256), tb, 0, stream>>>(Wq, WqP, HH);
  transpose_k<<<dim3(32,1),  tb, 0, stream>>>(Wc, WcT, VV, 2*HH);

  EncArgs EA;
  EA.x = x; EA.Wih0 = eWih0; EA.bih0 = ebih0; EA.bhh0 = ebhh0;
  EA.bih1 = ebih1; EA.bhh1 = ebhh1;
  EA.Whh0P = Whh0P; EA.Wih1P = Wih1P; EA.Whh1P = Whh1P;
  EA.gh_all = gh_all; EA.h0buf = h0buf; EA.h1buf = h1buf;
  EA.bar = (unsigned*)barbuf;

  DecArgs DA;
  DA.emb = emb;
  DA.bih0d = dbih0; DA.bhh0d = dbhh0; DA.bih1d = dbih1; DA.bhh1d = dbhh1;
  DA.bq = bq; DA.bc = bc;
  DA.Wih0P = dWih0P; DA.Whh0P = dWhh0P; DA.Wih1P = dWih1P; DA.Whh1P = dWhh1P;
  DA.WqP = WqP; DA.WcT = WcT;
  DA.h0init = h0buf;           // half 0 = h0 after step 1023
  DA.h1init = h1init;
  DA.dgh0 = dgh0; DA.dgh1 = dgh1; DA.h0d = h0d; DA.h1d = h1d;
  DA.h0n = h0n; DA.h1n = h1n; DA.qbuf = qbuf;
  DA.att = att; DA.pm = pmb; DA.pl = plb; DA.pctx = pctx;
  DA.tok = tok;
  DA.out_vec = out_vec; DA.out_attn = out_attn; DA.out_hid = out_hid;
  DA.bar = (unsigned*)(barbuf + 32);

  const size_t enc_elems = (size_t)BB*SS*HH;
  const size_t need32 = (off + enc_elems) * sizeof(float);
  if (ws_size >= need32) {
    float* out_enc = ws + off;
    EA.out_enc = out_enc; DA.out_enc = out_enc;
    launch_all<float>(EA, DA, stream);
  } else {
    __half* out_enc = reinterpret_cast<__half*>(ws + off);
    EA.out_enc = out_enc; DA.out_enc = out_enc;
    launch_all<__half>(EA, DA, stream);
  }
}

// Round 5
// 99833.209 us; speedup vs baseline: 1.2665x; 1.2665x over previous
//
#include <hip/hip_runtime.h>
#include <hip/hip_fp16.h>
#include <math.h>

#define HH 512
#define BB 128
#define SS 1024
#define TT 128
#define VV 32
#define GG 1536

#define ENC_BLOCKS 384
#define DEC_BLOCKS 256

#define SCOPE_AGENT __HIP_MEMORY_SCOPE_AGENT

__device__ __forceinline__ float sigm(float v){ return 1.f/(1.f+expf(-v)); }
__device__ __forceinline__ float fast_tanh(float x){
  float ax = fabsf(x);
  float t = expf(-2.f*ax);
  float r = (1.f - t)/(1.f + t);
  return copysignf(r, x);
}
__device__ __forceinline__ float gru_out(float gir, float giz, float gin,
                                         float ghr, float ghz, float ghn, float hp){
  float r = sigm(gir + ghr);
  float z = sigm(giz + ghz);
  float n = fast_tanh(fmaf(r, ghn, gin));
  return (1.f - z)*n + z*hp;
}

// ---- cache-bypassing (coherence-point) loads for cross-block data ----
__device__ __forceinline__ float2 byp2(const float* p){
  unsigned long long v = __hip_atomic_load((const unsigned long long*)p,
                                           __ATOMIC_RELAXED, SCOPE_AGENT);
  float2 r;
  r.x = __uint_as_float((unsigned)(v & 0xffffffffull));
  r.y = __uint_as_float((unsigned)(v >> 32));
  return r;
}
__device__ __forceinline__ float byp1(const float* p){
  return __uint_as_float(__hip_atomic_load((const unsigned*)p,
                                           __ATOMIC_RELAXED, SCOPE_AGENT));
}
__device__ __forceinline__ int byp1i(const int* p){
  return (int)__hip_atomic_load((const unsigned*)p, __ATOMIC_RELAXED, SCOPE_AGENT);
}

struct F8 { float v[8]; };
__device__ __forceinline__ F8 load8(const float* p){
  F8 r;
  float4 a = *reinterpret_cast<const float4*>(p);
  float4 b = *reinterpret_cast<const float4*>(p+4);
  r.v[0]=a.x; r.v[1]=a.y; r.v[2]=a.z; r.v[3]=a.w;
  r.v[4]=b.x; r.v[5]=b.y; r.v[6]=b.z; r.v[7]=b.w;
  return r;
}
__device__ __forceinline__ F8 load8(const __half* p){
  F8 r;
  union { float4 f4; __half2 h2[4]; } u;
  u.f4 = *reinterpret_cast<const float4*>(p);
  #pragma unroll
  for (int i=0;i<4;i++){ float2 f = __half22float2(u.h2[i]); r.v[2*i]=f.x; r.v[2*i+1]=f.y; }
  return r;
}
__device__ __forceinline__ void store_enc(float* p, float v){ *p = v; }
__device__ __forceinline__ void store_enc(__half* p, float v){ *p = __float2half(v); }

// ---- two-level grid barrier: release-only (no L2 invalidate) ----
// ctr: u32 array; group counters at [grp*16], root at [128]. 64B padded.
__device__ __forceinline__ void gbar(unsigned* ctr, int grp, unsigned bpg,
                                     unsigned ngrp, unsigned ep){
  __syncthreads();    // compiler emits waitcnt vmcnt(0) before s_barrier
  if (threadIdx.x == 0) {
    unsigned old = __hip_atomic_fetch_add(&ctr[grp*16], 1u,
                                          __ATOMIC_RELEASE, SCOPE_AGENT);
    if (old == ep*bpg + (bpg - 1))
      __hip_atomic_fetch_add(&ctr[128], 1u, __ATOMIC_RELEASE, SCOPE_AGENT);
    while (__hip_atomic_load(&ctr[128], __ATOMIC_RELAXED, SCOPE_AGENT)
           < (ep + 1u)*ngrp)
      __builtin_amdgcn_s_sleep(4);
    __builtin_amdgcn_sched_barrier(0);
  }
  __syncthreads();
}

// ---------- transpose (Wc only) ----------
__global__ void transpose_k(const float* __restrict__ src, float* __restrict__ dst,
                            int R, int C){
  __shared__ float tile[32][33];
  int c0 = blockIdx.x*32, r0 = blockIdx.y*32;
  int tx = threadIdx.x & 31, ty = threadIdx.x >> 5;
  for (int i = ty; i < 32; i += 8){
    int r = r0 + i, c = c0 + tx;
    tile[i][tx] = (r < R && c < C) ? src[(size_t)r*C + c] : 0.f;
  }
  __syncthreads();
  for (int i = ty; i < 32; i += 8){
    int c = c0 + i, r = r0 + tx;
    if (c < C && r < R) dst[(size_t)c*R + r] = tile[tx][i];
  }
}

// ---------- k-panel pack: W[R][512] -> chunk-major float4 panels ----------
__global__ void pack_w(const float* __restrict__ src, float* __restrict__ dst, int R){
  int idx = blockIdx.x*256 + threadIdx.x;
  int r = idx >> 9, k = idx & 511;
  dst[((size_t)(k>>2)*R + r)*4 + (k&3)] = src[idx];
}

// ---------- dot: 8 batches x 1 row over k=512; prefetch depth 4 ----------
__device__ __forceinline__ void dot8p(const float4* __restrict__ wp, int row, int NR,
                                      const float4* sh4, float acc[8]){
  const float4* p = wp + row;
  float4 w0 = p[0];
  float4 w1 = p[(size_t)NR];
  float4 w2 = p[(size_t)NR*2];
  float4 w3 = p[(size_t)NR*3];
  for (int kc = 0; kc < 128; kc += 4) {
    float4 n0 = p[(size_t)NR*(kc+4)];     // slack-padded allocation
    float4 n1 = p[(size_t)NR*(kc+5)];
    float4 n2 = p[(size_t)NR*(kc+6)];
    float4 n3 = p[(size_t)NR*(kc+7)];
    #pragma unroll
    for (int i = 0; i < 8; i++) {
      float4 ha = sh4[i*128 + kc + 0];
      float4 hb = sh4[i*128 + kc + 1];
      float4 hc = sh4[i*128 + kc + 2];
      float4 hd = sh4[i*128 + kc + 3];
      float a = acc[i];
      a = fmaf(w0.x,ha.x,a); a = fmaf(w0.y,ha.y,a); a = fmaf(w0.z,ha.z,a); a = fmaf(w0.w,ha.w,a);
      a = fmaf(w1.x,hb.x,a); a = fmaf(w1.y,hb.y,a); a = fmaf(w1.z,hb.z,a); a = fmaf(w1.w,hb.w,a);
      a = fmaf(w2.x,hc.x,a); a = fmaf(w2.y,hc.y,a); a = fmaf(w2.z,hc.z,a); a = fmaf(w2.w,hc.w,a);
      a = fmaf(w3.x,hd.x,a); a = fmaf(w3.y,hd.y,a); a = fmaf(w3.z,hd.z,a); a = fmaf(w3.w,hd.w,a);
      acc[i] = a;
    }
    w0=n0; w1=n1; w2=n2; w3=n3;
  }
}

// ================= persistent encoder =================
// gh_all layout: [2][3][GG rows][BB]  (pb, slot, gate-row, batch)
struct EncArgs {
  const float *x, *Wih0, *bih0, *bhh0, *bih1, *bhh1;
  const float *Whh0P, *Wih1P, *Whh1P;
  float *gh_all, *h0buf, *h1buf;
  void *out_enc;
  unsigned *ctr;
};

template<typename ET>
__global__ __launch_bounds__(192) void enc_persist(EncArgs A)
{
  __shared__ float4 sh4[1024];
  float* shs = (float*)sh4;
  const int bid = blockIdx.x;
  const int xcd = bid & 7, j = bid >> 3;
  const int rc  = xcd*3 + (j % 3);
  const int bch = j / 3;
  const int m   = rc >> 3;
  const int b0  = bch*8;
  const int tid = threadIdx.x;
  ET* out_enc = (ET*)A.out_enc;

  for (int p = 0; p <= SS; ++p) {
    const int pb = p & 1;
    const bool active = !((m == 0 && p >= SS) || (m >= 1 && p < 1));
    if (active) {
      if (m <= 1) {
        float* h0w = A.h0buf + (size_t)pb*BB*HH;
        const float* h0r = A.h0buf + (size_t)(1-pb)*BB*HH;
        const float* g0 = A.gh_all + ((size_t)(1-pb)*3 + 0)*(size_t)GG*BB;
        for (int u = tid; u < 4*HH; u += 192) {
          int bp = u >> 9, e = u & (HH-1);
          int b = b0 + bp*2;
          float hv0, hv1;
          if (p == 0) { hv0 = 0.f; hv1 = 0.f; }
          else {
            int t0 = p - 1;
            float2 xa = *(const float2*)&A.x[((size_t)b*SS + t0)*2];
            float2 xb = *(const float2*)&A.x[((size_t)(b+1)*SS + t0)*2];
            float2 wr = *(const float2*)&A.Wih0[e*2];
            float2 wz = *(const float2*)&A.Wih0[(HH+e)*2];
            float2 wn = *(const float2*)&A.Wih0[(2*HH+e)*2];
            float2 ghr = byp2(&g0[(size_t)e*BB + b]);
            float2 ghz = byp2(&g0[(size_t)(HH+e)*BB + b]);
            float2 ghn = byp2(&g0[(size_t)(2*HH+e)*BB + b]);
            float bir = A.bih0[e], biz = A.bih0[HH+e], bin_ = A.bih0[2*HH+e];
            float bhr = A.bhh0[e], bhz = A.bhh0[HH+e], bhn = A.bhh0[2*HH+e];
            float hp0 = (p == 1) ? 0.f : h0r[(size_t)b*HH + e];
            float hp1 = (p == 1) ? 0.f : h0r[(size_t)(b+1)*HH + e];
            hv0 = gru_out(fmaf(xa.x,wr.x,fmaf(xa.y,wr.y,bir)),
                          fmaf(xa.x,wz.x,fmaf(xa.y,wz.y,biz)),
                          fmaf(xa.x,wn.x,fmaf(xa.y,wn.y,bin_)),
                          ghr.x+bhr, ghz.x+bhz, ghn.x+bhn, hp0);
            hv1 = gru_out(fmaf(xb.x,wr.x,fmaf(xb.y,wr.y,bir)),
                          fmaf(xb.x,wz.x,fmaf(xb.y,wz.y,biz)),
                          fmaf(xb.x,wn.x,fmaf(xb.y,wn.y,bin_)),
                          ghr.y+bhr, ghz.y+bhz, ghn.y+bhn, hp1);
          }
          h0w[(size_t)b*HH + e] = hv0;
          h0w[(size_t)(b+1)*HH + e] = hv1;
          shs[(bp*2)*HH + e] = hv0;
          shs[(bp*2+1)*HH + e] = hv1;
        }
      } else {
        float* h1w = A.h1buf + (size_t)pb*BB*HH;
        const float* h1r = A.h1buf + (size_t)(1-pb)*BB*HH;
        const float* g1 = A.gh_all + ((size_t)(1-pb)*3 + 1)*(size_t)GG*BB;
        const float* g2 = A.gh_all + ((size_t)(1-pb)*3 + 2)*(size_t)GG*BB;
        for (int u = tid; u < 4*HH; u += 192) {
          int bp = u >> 9, e = u & (HH-1);
          int b = b0 + bp*2;
          float hv0, hv1;
          if (p <= 1) { hv0 = 0.f; hv1 = 0.f; }
          else {
            float2 gir = byp2(&g1[(size_t)e*BB + b]);
            float2 giz = byp2(&g1[(size_t)(HH+e)*BB + b]);
            float2 gin = byp2(&g1[(size_t)(2*HH+e)*BB + b]);
            float2 ghr = byp2(&g2[(size_t)e*BB + b]);
            float2 ghz = byp2(&g2[(size_t)(HH+e)*BB + b]);
            float2 ghn = byp2(&g2[(size_t)(2*HH+e)*BB + b]);
            float bir = A.bih1[e], biz = A.bih1[HH+e], bin_ = A.bih1[2*HH+e];
            float bhr = A.bhh1[e], bhz = A.bhh1[HH+e], bhn = A.bhh1[2*HH+e];
            float hp0 = (p == 2) ? 0.f : h1r[(size_t)b*HH + e];
            float hp1 = (p == 2) ? 0.f : h1r[(size_t)(b+1)*HH + e];
            hv0 = gru_out(gir.x+bir, giz.x+biz, gin.x+bin_,
                          ghr.x+bhr, ghz.x+bhz, ghn.x+bhn, hp0);
            hv1 = gru_out(gir.y+bir, giz.y+biz, gin.y+bin_,
                          ghr.y+bhr, ghz.y+bhz, ghn.y+bhn, hp1);
          }
          h1w[(size_t)b*HH + e] = hv0;
          h1w[(size_t)(b+1)*HH + e] = hv1;
          shs[(bp*2)*HH + e] = hv0;
          shs[(bp*2+1)*HH + e] = hv1;
          if (p >= 2) {
            store_enc(out_enc + ((size_t)b*SS + (p-2))*HH + e, hv0);
            store_enc(out_enc + ((size_t)(b+1)*SS + (p-2))*HH + e, hv1);
          }
        }
      }
      __syncthreads();

      const float4* WP = (const float4*)((m == 0) ? A.Whh0P : (m == 1) ? A.Wih1P : A.Whh1P);
      const int wv = tid >> 6, lane = tid & 63;
      const int row = (rc & 7)*192 + wv*64 + lane;
      float acc[8] = {0,0,0,0,0,0,0,0};
      dot8p(WP, row, GG, sh4, acc);
      float* dst = A.gh_all + ((size_t)pb*3 + m)*(size_t)GG*BB + (size_t)row*BB + b0;
      *(float4*)dst       = make_float4(acc[0], acc[1], acc[2], acc[3]);
      *(float4*)(dst + 4) = make_float4(acc[4], acc[5], acc[6], acc[7]);
    }
    gbar(A.ctr, xcd, 48u, 8u, (unsigned)p);
  }
}

// ---------- bridge: finalize h1[1023] (separate kernel => coherent) ----------
template<typename ET>
__global__ void enc_bridge(
    const float* __restrict__ gh_all, const float* __restrict__ h1buf,
    const float* __restrict__ bih1, const float* __restrict__ bhh1,
    float* __restrict__ h1init, ET* __restrict__ out_enc)
{
  int idx = blockIdx.x*256 + threadIdx.x;   // 65536
  int b = idx >> 9, e = idx & (HH-1);
  const float* g1 = gh_all + (size_t)1*GG*BB;   // pb=0 slot1
  const float* g2 = gh_all + (size_t)2*GG*BB;   // pb=0 slot2
  float gir = g1[(size_t)e*BB + b]        + bih1[e];
  float giz = g1[(size_t)(HH+e)*BB + b]   + bih1[HH+e];
  float gin = g1[(size_t)(2*HH+e)*BB + b] + bih1[2*HH+e];
  float ghr = g2[(size_t)e*BB + b]        + bhh1[e];
  float ghz = g2[(size_t)(HH+e)*BB + b]   + bhh1[HH+e];
  float ghn = g2[(size_t)(2*HH+e)*BB + b] + bhh1[2*HH+e];
  float hp = h1buf[(size_t)b*HH + e];           // h1[1022] (half 0)
  float hv = gru_out(gir, giz, gin, ghr, ghz, ghn, hp);
  h1init[(size_t)b*HH + e] = hv;
  store_enc(out_enc + ((size_t)b*SS + (SS-1))*HH + e, hv);
}

// ================= persistent decoder =================
// dgh layout: [2][2][GG rows][BB]; qbuf: [HH rows][BB]
struct DecArgs {
  const float *emb;
  const float *bih0d, *bhh0d, *bih1d, *bhh1d, *bq, *bc;
  const float *Wih0P, *Whh0P, *Wih1P, *Whh1P, *WqP, *WcT;
  const float *h0init, *h1init;
  float *dgh0, *dgh1, *h0d, *h1d, *h0n, *h1n, *qbuf;
  float *att, *pm, *pl, *pctx;
  int *tok;
  void *out_enc;
  float *out_vec, *out_attn, *out_hid;
  unsigned *ctr;
};

template<typename ET>
__global__ __launch_bounds__(256) void dec_persist(DecArgs A)
{
  __shared__ float4 smem4[1024];
  float* smem = (float*)smem4;
  __shared__ float lm[4], ll[4];
  __shared__ float s_red[8][33];
  __shared__ int stok[8];
  const int bid = blockIdx.x;
  const int tid = threadIdx.x;
  const int wv = tid >> 6, lane = tid & 63;
  const int grp = bid & 7;
  ET* out_enc = (ET*)A.out_enc;
  unsigned ep = 0;

  for (int t = 0; t < TT; ++t) {
    const int db = t & 1;

    // ---- phase A: cell0 dots ----
    if (bid < 192) {
      const int m = bid / 96, v = bid % 96, rowu = v / 16, bch = v % 16, b0 = bch*8;
      if (m == 1) {
        const float* giB = A.dgh0 + ((size_t)(1-db)*2 + 0)*(size_t)GG*BB;
        const float* ghB = A.dgh0 + ((size_t)(1-db)*2 + 1)*(size_t)GG*BB;
        const float* hpB = A.h0d + (size_t)(1-db)*BB*HH;
        float* hw = A.h0d + (size_t)db*BB*HH;
        for (int u = tid; u < 4*HH; u += 256) {
          int bp = u >> 9, e = u & (HH-1);
          int b = b0 + bp*2;
          float hv0, hv1;
          if (t == 0) {
            hv0 = A.h0init[(size_t)b*HH + e];
            hv1 = A.h0init[(size_t)(b+1)*HH + e];
          } else {
            float2 gir = byp2(&giB[(size_t)e*BB + b]);
            float2 giz = byp2(&giB[(size_t)(HH+e)*BB + b]);
            float2 gin = byp2(&giB[(size_t)(2*HH+e)*BB + b]);
            float2 ghr = byp2(&ghB[(size_t)e*BB + b]);
            float2 ghz = byp2(&ghB[(size_t)(HH+e)*BB + b]);
            float2 ghn = byp2(&ghB[(size_t)(2*HH+e)*BB + b]);
            float bir=A.bih0d[e], biz=A.bih0d[HH+e], bin_=A.bih0d[2*HH+e];
            float bhr=A.bhh0d[e], bhz=A.bhh0d[HH+e], bhn=A.bhh0d[2*HH+e];
            float hp0, hp1;
            if (t == 1) { hp0 = A.h0init[(size_t)b*HH + e]; hp1 = A.h0init[(size_t)(b+1)*HH + e]; }
            else        { hp0 = byp1(&hpB[(size_t)b*HH + e]); hp1 = byp1(&hpB[(size_t)(b+1)*HH + e]); }
            hv0 = gru_out(gir.x+bir, giz.x+biz, gin.x+bin_, ghr.x+bhr, ghz.x+bhz, ghn.x+bhn, hp0);
            hv1 = gru_out(gir.y+bir, giz.y+biz, gin.y+bin_, ghr.y+bhr, ghz.y+bhz, ghn.y+bhn, hp1);
          }
          smem[(bp*2)*HH + e] = hv0;
          smem[(bp*2+1)*HH + e] = hv1;
          if (rowu == 0) {
            hw[(size_t)b*HH + e] = hv0;
            hw[(size_t)(b+1)*HH + e] = hv1;
          }
        }
      } else {
        if (tid < 8) stok[tid] = byp1i(A.tok + b0 + tid);
        __syncthreads();
        for (int u = tid; u < 4*HH; u += 256) {
          int bp = u >> 9, e = u & (HH-1);
          smem[(bp*2)*HH + e]   = A.emb[(size_t)stok[bp*2]*HH + e];
          smem[(bp*2+1)*HH + e] = A.emb[(size_t)stok[bp*2+1]*HH + e];
        }
      }
      __syncthreads();
      const float4* WP = (const float4*)((m == 0) ? A.Wih0P : A.Whh0P);
      const int row = rowu*256 + tid;
      float acc[8] = {0,0,0,0,0,0,0,0};
      dot8p(WP, row, GG, smem4, acc);
      float* dst = A.dgh0 + ((size_t)db*2 + m)*(size_t)GG*BB + (size_t)row*BB + b0;
      *(float4*)dst       = make_float4(acc[0], acc[1], acc[2], acc[3]);
      *(float4*)(dst + 4) = make_float4(acc[4], acc[5], acc[6], acc[7]);
    }
    gbar(A.ctr, grp, 32u, 8u, ep); ep++;

    // ---- phase B: cell1 dots ----
    if (bid < 192) {
      const int m = bid / 96, v = bid % 96, rowu = v / 16, bch = v % 16, b0 = bch*8;
      if (m == 0) {
        const float* giB = A.dgh0 + ((size_t)db*2 + 0)*(size_t)GG*BB;
        const float* ghB = A.dgh0 + ((size_t)db*2 + 1)*(size_t)GG*BB;
        const float* hpB = A.h0d + (size_t)db*BB*HH;
        for (int u = tid; u < 4*HH; u += 256) {
          int bp = u >> 9, e = u & (HH-1);
          int b = b0 + bp*2;
          float2 gir = byp2(&giB[(size_t)e*BB + b]);
          float2 giz = byp2(&giB[(size_t)(HH+e)*BB + b]);
          float2 gin = byp2(&giB[(size_t)(2*HH+e)*BB + b]);
          float2 ghr = byp2(&ghB[(size_t)e*BB + b]);
          float2 ghz = byp2(&ghB[(size_t)(HH+e)*BB + b]);
          float2 ghn = byp2(&ghB[(size_t)(2*HH+e)*BB + b]);
          float bir=A.bih0d[e], biz=A.bih0d[HH+e], bin_=A.bih0d[2*HH+e];
          float bhr=A.bhh0d[e], bhz=A.bhh0d[HH+e], bhn=A.bhh0d[2*HH+e];
          float hp0 = byp1(&hpB[(size_t)b*HH + e]);
          float hp1 = byp1(&hpB[(size_t)(b+1)*HH + e]);
          float hv0 = gru_out(gir.x+bir, giz.x+biz, gin.x+bin_, ghr.x+bhr, ghz.x+bhz, ghn.x+bhn, hp0);
          float hv1 = gru_out(gir.y+bir, giz.y+biz, gin.y+bin_, ghr.y+bhr, ghz.y+bhz, ghn.y+bhn, hp1);
          smem[(bp*2)*HH + e] = hv0;
          smem[(bp*2+1)*HH + e] = hv1;
          if (rowu == 0) {
            A.h0n[(size_t)b*HH + e] = hv0;
            A.h0n[(size_t)(b+1)*HH + e] = hv1;
          }
        }
      } else {
        const float* giB = A.dgh1 + ((size_t)(1-db)*2 + 0)*(size_t)GG*BB;
        const float* ghB = A.dgh1 + ((size_t)(1-db)*2 + 1)*(size_t)GG*BB;
        const float* hpB = A.h1d + (size_t)(1-db)*BB*HH;
        float* hw = A.h1d + (size_t)db*BB*HH;
        for (int u = tid; u < 4*HH; u += 256) {
          int bp = u >> 9, e = u & (HH-1);
          int b = b0 + bp*2;
          float hv0, hv1;
          if (t == 0) {
            hv0 = A.h1init[(size_t)b*HH + e];
            hv1 = A.h1init[(size_t)(b+1)*HH + e];
          } else {
            float2 gir = byp2(&giB[(size_t)e*BB + b]);
            float2 giz = byp2(&giB[(size_t)(HH+e)*BB + b]);
            float2 gin = byp2(&giB[(size_t)(2*HH+e)*BB + b]);
            float2 ghr = byp2(&ghB[(size_t)e*BB + b]);
            float2 ghz = byp2(&ghB[(size_t)(HH+e)*BB + b]);
            float2 ghn = byp2(&ghB[(size_t)(2*HH+e)*BB + b]);
            float bir=A.bih1d[e], biz=A.bih1d[HH+e], bin_=A.bih1d[2*HH+e];
            float bhr=A.bhh1d[e], bhz=A.bhh1d[HH+e], bhn=A.bhh1d[2*HH+e];
            float hp0, hp1;
            if (t == 1) { hp0 = A.h1init[(size_t)b*HH + e]; hp1 = A.h1init[(size_t)(b+1)*HH + e]; }
            else        { hp0 = byp1(&hpB[(size_t)b*HH + e]); hp1 = byp1(&hpB[(size_t)(b+1)*HH + e]); }
            hv0 = gru_out(gir.x+bir, giz.x+biz, gin.x+bin_, ghr.x+bhr, ghz.x+bhz, ghn.x+bhn, hp0);
            hv1 = gru_out(gir.y+bir, giz.y+biz, gin.y+bin_, ghr.y+bhr, ghz.y+bhz, ghn.y+bhn, hp1);
          }
          smem[(bp*2)*HH + e] = hv0;
          smem[(bp*2+1)*HH + e] = hv1;
          if (rowu == 0) {
            hw[(size_t)b*HH + e] = hv0;
            hw[(size_t)(b+1)*HH + e] = hv1;
          }
        }
      }
      __syncthreads();
      const float4* WP = (const float4*)((m == 0) ? A.Wih1P : A.Whh1P);
      const int row = rowu*256 + tid;
      float acc[8] = {0,0,0,0,0,0,0,0};
      dot8p(WP, row, GG, smem4, acc);
      float* dst = A.dgh1 + ((size_t)db*2 + m)*(size_t)GG*BB + (size_t)row*BB + b0;
      *(float4*)dst       = make_float4(acc[0], acc[1], acc[2], acc[3]);
      *(float4*)(dst + 4) = make_float4(acc[4], acc[5], acc[6], acc[7]);
    }
    gbar(A.ctr, grp, 32u, 8u, ep); ep++;

    // ---- phase C: h1n + q ----
    if (bid < 32) {
      const int rowu = bid & 1, bch = bid >> 1, b0 = bch*8;
      const float* giB = A.dgh1 + ((size_t)db*2 + 0)*(size_t)GG*BB;
      const float* ghB = A.dgh1 + ((size_t)db*2 + 1)*(size_t)GG*BB;
      const float* hpB = A.h1d + (size_t)db*BB*HH;
      for (int u = tid; u < 4*HH; u += 256) {
        int bp = u >> 9, e = u & (HH-1);
        int b = b0 + bp*2;
        float2 gir = byp2(&giB[(size_t)e*BB + b]);
        float2 giz = byp2(&giB[(size_t)(HH+e)*BB + b]);
        float2 gin = byp2(&giB[(size_t)(2*HH+e)*BB + b]);
        float2 ghr = byp2(&ghB[(size_t)e*BB + b]);
        float2 ghz = byp2(&ghB[(size_t)(HH+e)*BB + b]);
        float2 ghn = byp2(&ghB[(size_t)(2*HH+e)*BB + b]);
        float bir=A.bih1d[e], biz=A.bih1d[HH+e], bin_=A.bih1d[2*HH+e];
        float bhr=A.bhh1d[e], bhz=A.bhh1d[HH+e], bhn=A.bhh1d[2*HH+e];
        float hp0 = byp1(&hpB[(size_t)b*HH + e]);
        float hp1 = byp1(&hpB[(size_t)(b+1)*HH + e]);
        float hv0 = gru_out(gir.x+bir, giz.x+biz, gin.x+bin_, ghr.x+bhr, ghz.x+bhz, ghn.x+bhn, hp0);
        float hv1 = gru_out(gir.y+bir, giz.y+biz, gin.y+bin_, ghr.y+bhr, ghz.y+bhz, ghn.y+bhn, hp1);
        smem[(bp*2)*HH + e] = hv0;
        smem[(bp*2+1)*HH + e] = hv1;
        if (rowu == 0) {
          A.h1n[(size_t)b*HH + e] = hv0;
          A.h1n[(size_t)(b+1)*HH + e] = hv1;
        }
      }
      __syncthreads();
      const int row = rowu*256 + tid;
      float acc[8] = {0,0,0,0,0,0,0,0};
      dot8p((const float4*)A.WqP, row, HH, smem4, acc);
      float bqv = A.bq[row];
      float* dst = A.qbuf + (size_t)row*BB + b0;
      *(float4*)dst       = make_float4(acc[0]+bqv, acc[1]+bqv, acc[2]+bqv, acc[3]+bqv);
      *(float4*)(dst + 4) = make_float4(acc[4]+bqv, acc[5]+bqv, acc[6]+bqv, acc[7]+bqv);
    }
    gbar(A.ctr, grp, 32u, 8u, ep); ep++;

    // ---- phase D: attention (1024 units, 4 per block) ----
    for (int u = bid; u < BB*8; u += DEC_BLOCKS) {
      const int b = u >> 3, sc = u & 7;
      __syncthreads();
      F8 q;
      #pragma unroll
      for (int jj = 0; jj < 8; jj++)
        q.v[jj] = byp1(&A.qbuf[(size_t)(lane*8 + jj)*BB + b]);
      const ET* encb = out_enc + (size_t)b*SS*HH;
      float mrun = -1e30f, lrun = 0.f;
      float c[8] = {0,0,0,0,0,0,0,0};
      float attkeep = 0.f;
      const int sbase = sc*128 + wv*32;
      for (int ii = 0; ii < 32; ii++) {
        const F8 e = load8(encb + (size_t)(sbase + ii)*HH + lane*8);
        float d = 0.f;
        #pragma unroll
        for (int jj = 0; jj < 8; jj++) d = fmaf(q.v[jj], e.v[jj], d);
        #pragma unroll
        for (int off = 32; off >= 1; off >>= 1) d += __shfl_xor(d, off, 64);
        if (lane == ii) attkeep = d;
        float mnew = fmaxf(mrun, d);
        float scal = expf(mrun - mnew);
        float pv = expf(d - mnew);
        lrun = fmaf(lrun, scal, pv);
        #pragma unroll
        for (int jj = 0; jj < 8; jj++) c[jj] = fmaf(c[jj], scal, pv*e.v[jj]);
        mrun = mnew;
      }
      if (lane < 32) A.att[(size_t)b*SS + sbase + lane] = attkeep;
      if (lane == 0) { lm[wv] = mrun; ll[wv] = lrun; }
      #pragma unroll
      for (int jj = 0; jj < 8; jj++) smem[wv*HH + lane*8 + jj] = c[jj];
      __syncthreads();
      float mb = fmaxf(fmaxf(lm[0],lm[1]), fmaxf(lm[2],lm[3]));
      float e0w = expf(lm[0]-mb), e1w = expf(lm[1]-mb), e2w = expf(lm[2]-mb), e3w = expf(lm[3]-mb);
      if (tid == 0) {
        A.pm[b*8+sc] = mb;
        A.pl[b*8+sc] = e0w*ll[0] + e1w*ll[1] + e2w*ll[2] + e3w*ll[3];
      }
      for (int k2 = tid; k2 < HH; k2 += 256) {
        float s = e0w*smem[0*HH+k2] + e1w*smem[1*HH+k2] + e2w*smem[2*HH+k2] + e3w*smem[3*HH+k2];
        A.pctx[((size_t)b*8 + sc)*HH + k2] = s;
      }
    }
    gbar(A.ctr, grp, 32u, 8u, ep); ep++;

    // ---- phase E: combine + attn-out + logits + argmax ----
    if (bid < BB) {
      const int b = bid;
      float* s_hc = smem;
      float pmv[8], plv[8];
      #pragma unroll
      for (int c8 = 0; c8 < 8; c8++){
        pmv[c8] = byp1(&A.pm[b*8+c8]);
        plv[c8] = byp1(&A.pl[b*8+c8]);
      }
      float mg = pmv[0];
      #pragma unroll
      for (int c8 = 1; c8 < 8; c8++) mg = fmaxf(mg, pmv[c8]);
      float epm[8]; float lg = 0.f;
      #pragma unroll
      for (int c8 = 0; c8 < 8; c8++){ epm[c8] = expf(pmv[c8]-mg); lg += epm[c8]*plv[c8]; }
      float inv_lg = 1.f/lg;
      {
        int k = tid*2;   // 512 elems in one pass
        float2 s2 = make_float2(0.f, 0.f);
        #pragma unroll
        for (int c8 = 0; c8 < 8; c8++){
          float2 pc = byp2(&A.pctx[((size_t)b*8+c8)*HH + k]);
          s2.x += epm[c8]*pc.x; s2.y += epm[c8]*pc.y;
        }
        float2 h2 = byp2(&A.h1n[(size_t)b*HH + k]);
        s_hc[HH + k]   = s2.x * inv_lg;
        s_hc[HH + k+1] = s2.y * inv_lg;
        s_hc[k]   = h2.x;
        s_hc[k+1] = h2.y;
      }
      __syncthreads();
      for (int s = tid*2; s < SS; s += 512) {
        float2 av = byp2(&A.att[(size_t)b*SS + s]);
        A.out_attn[((size_t)b*SS + s)*TT + t]     = expf(av.x - mg) * inv_lg;
        A.out_attn[((size_t)b*SS + s + 1)*TT + t] = expf(av.y - mg) * inv_lg;
      }
      const int v = tid & 31, part = tid >> 5;
      float pacc = 0.f;
      for (int k = part*128; k < part*128 + 128; k++)
        pacc = fmaf(s_hc[k], A.WcT[(size_t)k*VV + v], pacc);
      s_red[part][v] = pacc;
      __syncthreads();
      if (tid < 32) {
        float lv = A.bc[tid];
        #pragma unroll
        for (int c8 = 0; c8 < 8; c8++) lv += s_red[c8][tid];
        A.out_vec[((size_t)b*TT + t)*VV + tid] = lv;
        float bv = lv; int bi = tid;
        #pragma unroll
        for (int off = 16; off >= 1; off >>= 1) {
          float ov = __shfl_xor(bv, off, 64);
          int   oi = __shfl_xor(bi, off, 64);
          if (ov > bv || (ov == bv && oi < bi)) { bv = ov; bi = oi; }
        }
        if (tid == 0) A.tok[b] = bi;
      }
    }
    gbar(A.ctr, grp, 32u, 8u, ep); ep++;
  }

  // ---- final hidden-state output ----
  for (int i = bid*256 + tid; i < BB*HH; i += DEC_BLOCKS*256) {
    A.out_hid[i] = byp1(&A.h0n[i]);
    A.out_hid[BB*HH + i] = byp1(&A.h1n[i]);
  }
}

// ================= host =================
template<typename ET>
static void launch_all(EncArgs& EA, DecArgs& DA, hipStream_t stream) {
  void* ep[1] = { &EA };
  hipLaunchCooperativeKernel((const void*)&enc_persist<ET>, dim3(ENC_BLOCKS), dim3(192),
                             ep, 0, stream);
  enc_bridge<ET><<<dim3(256), dim3(256), 0, stream>>>(
      EA.gh_all, EA.h1buf, EA.bih1, EA.bhh1,
      (float*)DA.h1init, (ET*)EA.out_enc);
  void* dp[1] = { &DA };
  hipLaunchCooperativeKernel((const void*)&dec_persist<ET>, dim3(DEC_BLOCKS), dim3(256),
                             dp, 0, stream);
}

extern "C" void kernel_launch(void* const* d_in, const int* in_sizes, int n_in,
                              void* d_out, int out_size, void* d_ws, size_t ws_size,
                              hipStream_t stream) {
  const float* x      = (const float*)d_in[0];
  const float* emb    = (const float*)d_in[1];
  const float* eWih0  = (const float*)d_in[2];
  const float* eWhh0  = (const float*)d_in[3];
  const float* ebih0  = (const float*)d_in[4];
  const float* ebhh0  = (const float*)d_in[5];
  const float* eWih1  = (const float*)d_in[6];
  const float* eWhh1  = (const float*)d_in[7];
  const float* ebih1  = (const float*)d_in[8];
  const float* ebhh1  = (const float*)d_in[9];
  const float* dWih0  = (const float*)d_in[10];
  const float* dWhh0  = (const float*)d_in[11];
  const float* dbih0  = (const float*)d_in[12];
  const float* dbhh0  = (const float*)d_in[13];
  const float* dWih1  = (const float*)d_in[14];
  const float* dWhh1  = (const float*)d_in[15];
  const float* dbih1  = (const float*)d_in[16];
  const float* dbhh1  = (const float*)d_in[17];
  const float* Wq     = (const float*)d_in[18];
  const float* bq     = (const float*)d_in[19];
  const float* Wc     = (const float*)d_in[20];
  const float* bc     = (const float*)d_in[21];
  (void)in_sizes; (void)n_in; (void)out_size;

  float* ws = (float*)d_ws;
  size_t off = 0;
  auto alloc = [&](size_t n){ float* p = ws + off; off += n; return p; };
  const size_t PKB = (size_t)GG*HH + 32*GG;   // packed panel + prefetch slack
  const size_t PKQ = (size_t)HH*HH + 32*HH;

  float* gh_all  = alloc((size_t)2*3*GG*BB);
  float* dgh0    = alloc((size_t)2*2*GG*BB);
  float* dgh1    = alloc((size_t)2*2*GG*BB);
  float* h0buf   = alloc((size_t)2*BB*HH);
  float* h1buf   = alloc((size_t)2*BB*HH);
  float* h0d     = alloc((size_t)2*BB*HH);
  float* h1d     = alloc((size_t)2*BB*HH);
  float* h0n     = alloc((size_t)BB*HH);
  float* h1n     = alloc((size_t)BB*HH);
  float* h1init  = alloc((size_t)BB*HH);
  float* qbuf    = alloc((size_t)HH*BB);
  float* att     = alloc((size_t)BB*SS);
  float* pmb     = alloc((size_t)BB*8);
  float* plb     = alloc((size_t)BB*8);
  float* pctx    = alloc((size_t)BB*8*HH);
  int*   tok     = (int*)alloc((size_t)BB);
  unsigned* ctrs = (unsigned*)alloc((size_t)512);   // enc @0, dec @256
  float* Whh0P   = alloc(PKB);
  float* Wih1P   = alloc(PKB);
  float* Whh1P   = alloc(PKB);
  float* dWih0P  = alloc(PKB);
  float* dWhh0P  = alloc(PKB);
  float* dWih1P  = alloc(PKB);
  float* dWhh1P  = alloc(PKB);
  float* WqP     = alloc(PKQ);
  float* WcT     = alloc((size_t)2*HH*VV);

  float* out_vec  = (float*)d_out;
  float* out_hid  = (float*)d_out + (size_t)BB*TT*VV;
  float* out_attn = (float*)d_out + (size_t)BB*TT*VV + (size_t)2*BB*HH;

  hipMemsetAsync(ctrs, 0, 512*sizeof(unsigned), stream);
  hipMemsetAsync(tok, 0, BB*sizeof(int), stream);

  dim3 tb(256);
  pack_w<<<dim3(GG*HH/256), tb, 0, stream>>>(eWhh0, Whh0P, GG);
  pack_w<<<dim3(GG*HH/256), tb, 0, stream>>>(eWih1, Wih1P, GG);
  pack_w<<<dim3(GG*HH/256), tb, 0, stream>>>(eWhh1, Whh1P, GG);
  pack_w<<<dim3(GG*HH/256), tb, 0, stream>>>(dWih0, dWih0P, GG);
  pack_w<<<dim3(GG*HH/256), tb, 0, stream>>>(dWhh0, dWhh0P, GG);
  pack_w<<<dim3(GG*HH/256), tb, 0, stream>>>(dWih1, dWih1P, GG);
  pack_w<<<dim3(GG*HH/256), tb, 0, stream>>>(dWih1, dWih1P, GG);
  pack_w<<<dim3(GG*HH/256), tb, 0, stream>>>(dWhh1, dWhh1P, GG);
  pack_w<<<dim3(HH*HH/256), tb, 0, stream>>>(Wq, WqP, HH);
  transpose_k<<<dim3(32,1),  tb, 0, stream>>>(Wc, WcT, VV, 2*HH);

  EncArgs EA;
  EA.x = x; EA.Wih0 = eWih0; EA.bih0 = ebih0; EA.bhh0 = ebhh0;
  EA.bih1 = ebih1; EA.bhh1 = ebhh1;
  EA.Whh0P = Whh0P; EA.Wih1P = Wih1P; EA.Whh1P = Whh1P;
  EA.gh_all = gh_all; EA.h0buf = h0buf; EA.h1buf = h1buf;
  EA.ctr = ctrs;

  DecArgs DA;
  DA.emb = emb;
  DA.bih0d = dbih0; DA.bhh0d = dbhh0; DA.bih1d = dbih1; DA.bhh1d = dbhh1;
  DA.bq = bq; DA.bc = bc;
  DA.Wih0P = dWih0P; DA.Whh0P = dWhh0P; DA.Wih1P = dWih1P; DA.Whh1P = dWhh1P;
  DA.WqP = WqP; DA.WcT = WcT;
  DA.h0init = h0buf;           // half 0 = h0 after step 1023
  DA.h1init = h1init;
  DA.dgh0 = dgh0; DA.dgh1 = dgh1; DA.h0d = h0d; DA.h1d = h1d;
  DA.h0n = h0n; DA.h1n = h1n; DA.qbuf = qbuf;
  DA.att = att; DA.pm = pmb; DA.pl = plb; DA.pctx = pctx;
  DA.tok = tok;
  DA.out_vec = out_vec; DA.out_attn = out_attn; DA.out_hid = out_hid;
  DA.ctr = ctrs + 256;

  const size_t enc_elems = (size_t)BB*SS*HH;
  const size_t need32 = (off + enc_elems) * sizeof(float);
  if (ws_size >= need32) {
    float* out_enc = ws + off;
    EA.out_enc = out_enc; DA.out_enc = out_enc;
    launch_all<float>(EA, DA, stream);
  } else {
    __half* out_enc = reinterpret_cast<__half*>(ws + off);
    EA.out_enc = out_enc; DA.out_enc = out_enc;
    launch_all<__half>(EA, DA, stream);
  }
}

// Round 10
// 97696.185 us; speedup vs baseline: 1.2942x; 1.0219x over previous
//
#include <hip/hip_runtime.h>
#include <hip/hip_fp16.h>
#include <math.h>

#define HH 512
#define BB 128
#define SS 1024
#define TT 128
#define VV 32
#define GG 1536

#define ENC_BLOCKS 384
#define DEC_BLOCKS 256

#define SCOPE_AGENT __HIP_MEMORY_SCOPE_AGENT

__device__ __forceinline__ float fexp(float x){ return __expf(x); }
__device__ __forceinline__ float frcp(float x){ return __builtin_amdgcn_rcpf(x); }
__device__ __forceinline__ float sigm(float v){ return frcp(1.f + fexp(-v)); }
__device__ __forceinline__ float fast_tanh(float x){
  float ax = fabsf(x);
  float t = fexp(-2.f*ax);
  float r = (1.f - t)*frcp(1.f + t);
  return copysignf(r, x);
}
__device__ __forceinline__ float gru_out(float gir, float giz, float gin,
                                         float ghr, float ghz, float ghn, float hp){
  float r = sigm(gir + ghr);
  float z = sigm(giz + ghz);
  float n = fast_tanh(fmaf(r, ghn, gin));
  return (1.f - z)*n + z*hp;
}

// ---- cache-bypassing (coherence-point) loads for cross-block data ----
__device__ __forceinline__ float2 byp2(const float* p){
  unsigned long long v = __hip_atomic_load((const unsigned long long*)p,
                                           __ATOMIC_RELAXED, SCOPE_AGENT);
  float2 r;
  r.x = __uint_as_float((unsigned)(v & 0xffffffffull));
  r.y = __uint_as_float((unsigned)(v >> 32));
  return r;
}
__device__ __forceinline__ float byp1(const float* p){
  return __uint_as_float(__hip_atomic_load((const unsigned*)p,
                                           __ATOMIC_RELAXED, SCOPE_AGENT));
}
__device__ __forceinline__ int byp1i(const int* p){
  return (int)__hip_atomic_load((const unsigned*)p, __ATOMIC_RELAXED, SCOPE_AGENT);
}

struct F8 { float v[8]; };
__device__ __forceinline__ F8 load8(const float* p){
  F8 r;
  float4 a = *reinterpret_cast<const float4*>(p);
  float4 b = *reinterpret_cast<const float4*>(p+4);
  r.v[0]=a.x; r.v[1]=a.y; r.v[2]=a.z; r.v[3]=a.w;
  r.v[4]=b.x; r.v[5]=b.y; r.v[6]=b.z; r.v[7]=b.w;
  return r;
}
__device__ __forceinline__ F8 load8(const __half* p){
  F8 r;
  union { float4 f4; __half2 h2[4]; } u;
  u.f4 = *reinterpret_cast<const float4*>(p);
  #pragma unroll
  for (int i=0;i<4;i++){ float2 f = __half22float2(u.h2[i]); r.v[2*i]=f.x; r.v[2*i+1]=f.y; }
  return r;
}
__device__ __forceinline__ void store_enc(float* p, float v){ *p = v; }
__device__ __forceinline__ void store_enc(__half* p, float v){ *p = __float2half(v); }

// ---- two-level grid barrier: release-only (no L2 invalidate) ----
__device__ __forceinline__ void gbar(unsigned* ctr, int grp, unsigned bpg,
                                     unsigned ngrp, unsigned ep){
  __syncthreads();
  if (threadIdx.x == 0) {
    unsigned old = __hip_atomic_fetch_add(&ctr[grp*16], 1u,
                                          __ATOMIC_RELEASE, SCOPE_AGENT);
    if (old == ep*bpg + (bpg - 1))
      __hip_atomic_fetch_add(&ctr[128], 1u, __ATOMIC_RELEASE, SCOPE_AGENT);
    while (__hip_atomic_load(&ctr[128], __ATOMIC_RELAXED, SCOPE_AGENT)
           < (ep + 1u)*ngrp)
      __builtin_amdgcn_s_sleep(4);
    __builtin_amdgcn_sched_barrier(0);
  }
  __syncthreads();
}

// ---------- transpose (Wc only) ----------
__global__ void transpose_k(const float* __restrict__ src, float* __restrict__ dst,
                            int R, int C){
  __shared__ float tile[32][33];
  int c0 = blockIdx.x*32, r0 = blockIdx.y*32;
  int tx = threadIdx.x & 31, ty = threadIdx.x >> 5;
  for (int i = ty; i < 32; i += 8){
    int r = r0 + i, c = c0 + tx;
    tile[i][tx] = (r < R && c < C) ? src[(size_t)r*C + c] : 0.f;
  }
  __syncthreads();
  for (int i = ty; i < 32; i += 8){
    int c = c0 + i, r = r0 + tx;
    if (c < C && r < R) dst[(size_t)c*R + r] = tile[tx][i];
  }
}

// ---------- k-panel pack: W[R][512] -> chunk-major float4 panels ----------
__global__ void pack_w(const float* __restrict__ src, float* __restrict__ dst, int R){
  int idx = blockIdx.x*256 + threadIdx.x;
  int r = idx >> 9, k = idx & 511;
  dst[((size_t)(k>>2)*R + r)*4 + (k&3)] = src[idx];
}

// ---------- dot: 8 batches x 1 row over k=512; prefetch depth 4 ----------
__device__ __forceinline__ void dot8p(const float4* __restrict__ wp, int row, int NR,
                                      const float4* sh4, float acc[8]){
  const float4* p = wp + row;
  float4 w0 = p[0];
  float4 w1 = p[(size_t)NR];
  float4 w2 = p[(size_t)NR*2];
  float4 w3 = p[(size_t)NR*3];
  for (int kc = 0; kc < 128; kc += 4) {
    float4 n0 = p[(size_t)NR*(kc+4)];     // slack-padded allocation
    float4 n1 = p[(size_t)NR*(kc+5)];
    float4 n2 = p[(size_t)NR*(kc+6)];
    float4 n3 = p[(size_t)NR*(kc+7)];
    #pragma unroll
    for (int i = 0; i < 8; i++) {
      float4 ha = sh4[i*128 + kc + 0];
      float4 hb = sh4[i*128 + kc + 1];
      float4 hc = sh4[i*128 + kc + 2];
      float4 hd = sh4[i*128 + kc + 3];
      float a = acc[i];
      a = fmaf(w0.x,ha.x,a); a = fmaf(w0.y,ha.y,a); a = fmaf(w0.z,ha.z,a); a = fmaf(w0.w,ha.w,a);
      a = fmaf(w1.x,hb.x,a); a = fmaf(w1.y,hb.y,a); a = fmaf(w1.z,hb.z,a); a = fmaf(w1.w,hb.w,a);
      a = fmaf(w2.x,hc.x,a); a = fmaf(w2.y,hc.y,a); a = fmaf(w2.z,hc.z,a); a = fmaf(w2.w,hc.w,a);
      a = fmaf(w3.x,hd.x,a); a = fmaf(w3.y,hd.y,a); a = fmaf(w3.z,hd.z,a); a = fmaf(w3.w,hd.w,a);
      acc[i] = a;
    }
    w0=n0; w1=n1; w2=n2; w3=n3;
  }
}

// ================= persistent encoder =================
// gh layout: [2 pb][3 slot][GG rows][BB]
struct EncArgs {
  const float *x, *Wih0, *bih0, *bhh0, *bih1, *bhh1;
  const float *Whh0P, *Wih1P, *Whh1P;
  float *gh, *h0buf, *h1buf;
  void *out_enc;
  unsigned *ctr;
};

template<typename ET>
__global__ __launch_bounds__(192) void enc_persist(EncArgs A)
{
  __shared__ float4 sh4[1024];
  float* shs = (float*)sh4;
  const int bid = blockIdx.x;
  const int xcd = bid & 7, j = bid >> 3;
  const int rc  = xcd*3 + (j % 3);
  const int bch = j / 3;
  const int m   = rc >> 3;
  const int b0  = bch*8;
  const int tid = threadIdx.x;
  ET* out_enc = (ET*)A.out_enc;

  for (int p = 0; p <= SS; ++p) {
    const int pb = p & 1;
    const bool active = !((m == 0 && p >= SS) || (m >= 1 && p < 1));
    if (active) {
      if (m <= 1) {
        float* h0w = A.h0buf + (size_t)pb*BB*HH;
        const float* h0r = A.h0buf + (size_t)(1-pb)*BB*HH;
        const float* g0 = A.gh + ((size_t)(1-pb)*3 + 0)*(size_t)GG*BB;
        for (int u = tid; u < 4*HH; u += 192) {
          int bp = u >> 9, e = u & (HH-1);
          int b = b0 + bp*2;
          float hv0, hv1;
          if (p == 0) { hv0 = 0.f; hv1 = 0.f; }
          else {
            int t0 = p - 1;
            float2 xa = *(const float2*)&A.x[((size_t)b*SS + t0)*2];
            float2 xb = *(const float2*)&A.x[((size_t)(b+1)*SS + t0)*2];
            float2 wr = *(const float2*)&A.Wih0[e*2];
            float2 wz = *(const float2*)&A.Wih0[(HH+e)*2];
            float2 wn = *(const float2*)&A.Wih0[(2*HH+e)*2];
            float2 ghr = byp2(&g0[(size_t)e*BB + b]);
            float2 ghz = byp2(&g0[(size_t)(HH+e)*BB + b]);
            float2 ghn = byp2(&g0[(size_t)(2*HH+e)*BB + b]);
            float bir = A.bih0[e], biz = A.bih0[HH+e], bin_ = A.bih0[2*HH+e];
            float bhr = A.bhh0[e], bhz = A.bhh0[HH+e], bhn = A.bhh0[2*HH+e];
            float hp0 = (p == 1) ? 0.f : h0r[(size_t)b*HH + e];
            float hp1 = (p == 1) ? 0.f : h0r[(size_t)(b+1)*HH + e];
            hv0 = gru_out(fmaf(xa.x,wr.x,fmaf(xa.y,wr.y,bir)),
                          fmaf(xa.x,wz.x,fmaf(xa.y,wz.y,biz)),
                          fmaf(xa.x,wn.x,fmaf(xa.y,wn.y,bin_)),
                          ghr.x+bhr, ghz.x+bhz, ghn.x+bhn, hp0);
            hv1 = gru_out(fmaf(xb.x,wr.x,fmaf(xb.y,wr.y,bir)),
                          fmaf(xb.x,wz.x,fmaf(xb.y,wz.y,biz)),
                          fmaf(xb.x,wn.x,fmaf(xb.y,wn.y,bin_)),
                          ghr.y+bhr, ghz.y+bhz, ghn.y+bhn, hp1);
          }
          h0w[(size_t)b*HH + e] = hv0;
          h0w[(size_t)(b+1)*HH + e] = hv1;
          shs[(bp*2)*HH + e] = hv0;
          shs[(bp*2+1)*HH + e] = hv1;
        }
      } else {
        float* h1w = A.h1buf + (size_t)pb*BB*HH;
        const float* h1r = A.h1buf + (size_t)(1-pb)*BB*HH;
        const float* g1 = A.gh + ((size_t)(1-pb)*3 + 1)*(size_t)GG*BB;
        const float* g2 = A.gh + ((size_t)(1-pb)*3 + 2)*(size_t)GG*BB;
        for (int u = tid; u < 4*HH; u += 192) {
          int bp = u >> 9, e = u & (HH-1);
          int b = b0 + bp*2;
          float hv0, hv1;
          if (p <= 1) { hv0 = 0.f; hv1 = 0.f; }
          else {
            float2 gir = byp2(&g1[(size_t)e*BB + b]);
            float2 giz = byp2(&g1[(size_t)(HH+e)*BB + b]);
            float2 gin = byp2(&g1[(size_t)(2*HH+e)*BB + b]);
            float2 ghr = byp2(&g2[(size_t)e*BB + b]);
            float2 ghz = byp2(&g2[(size_t)(HH+e)*BB + b]);
            float2 ghn = byp2(&g2[(size_t)(2*HH+e)*BB + b]);
            float bir = A.bih1[e], biz = A.bih1[HH+e], bin_ = A.bih1[2*HH+e];
            float bhr = A.bhh1[e], bhz = A.bhh1[HH+e], bhn = A.bhh1[2*HH+e];
            float hp0 = (p == 2) ? 0.f : h1r[(size_t)b*HH + e];
            float hp1 = (p == 2) ? 0.f : h1r[(size_t)(b+1)*HH + e];
            hv0 = gru_out(gir.x+bir, giz.x+biz, gin.x+bin_,
                          ghr.x+bhr, ghz.x+bhz, ghn.x+bhn, hp0);
            hv1 = gru_out(gir.y+bir, giz.y+biz, gin.y+bin_,
                          ghr.y+bhr, ghz.y+bhz, ghn.y+bhn, hp1);
          }
          h1w[(size_t)b*HH + e] = hv0;
          h1w[(size_t)(b+1)*HH + e] = hv1;
          shs[(bp*2)*HH + e] = hv0;
          shs[(bp*2+1)*HH + e] = hv1;
          if (p >= 2) {
            store_enc(out_enc + ((size_t)b*SS + (p-2))*HH + e, hv0);
            store_enc(out_enc + ((size_t)(b+1)*SS + (p-2))*HH + e, hv1);
          }
        }
      }
      __syncthreads();

      const float4* WP = (const float4*)((m == 0) ? A.Whh0P : (m == 1) ? A.Wih1P : A.Whh1P);
      const int wv = tid >> 6, lane = tid & 63;
      const int row = (rc & 7)*192 + wv*64 + lane;
      float acc[8] = {0,0,0,0,0,0,0,0};
      dot8p(WP, row, GG, sh4, acc);
      float* dst = A.gh + ((size_t)pb*3 + m)*(size_t)GG*BB + (size_t)row*BB + b0;
      *(float4*)dst       = make_float4(acc[0], acc[1], acc[2], acc[3]);
      *(float4*)(dst + 4) = make_float4(acc[4], acc[5], acc[6], acc[7]);
    }
    gbar(A.ctr, xcd, 48u, 8u, (unsigned)p);
  }
}

// ---------- bridge: finalize h1[1023] ----------
template<typename ET>
__global__ void enc_bridge(
    const float* __restrict__ gh, const float* __restrict__ h1buf,
    const float* __restrict__ bih1, const float* __restrict__ bhh1,
    float* __restrict__ h1init, ET* __restrict__ out_enc)
{
  int idx = blockIdx.x*256 + threadIdx.x;   // 65536
  int b = idx >> 9, e = idx & (HH-1);
  const float* g1 = gh + (size_t)1*GG*BB;   // pb=0 slot1
  const float* g2 = gh + (size_t)2*GG*BB;   // pb=0 slot2
  float gir = g1[(size_t)e*BB + b]        + bih1[e];
  float giz = g1[(size_t)(HH+e)*BB + b]   + bih1[HH+e];
  float gin = g1[(size_t)(2*HH+e)*BB + b] + bih1[2*HH+e];
  float ghr = g2[(size_t)e*BB + b]        + bhh1[e];
  float ghz = g2[(size_t)(HH+e)*BB + b]   + bhh1[HH+e];
  float ghn = g2[(size_t)(2*HH+e)*BB + b] + bhh1[2*HH+e];
  float hp = h1buf[(size_t)b*HH + e];           // h1[1022] (half 0)
  float hv = gru_out(gir, giz, gin, ghr, ghz, ghn, hp);
  h1init[(size_t)b*HH + e] = hv;
  store_enc(out_enc + ((size_t)b*SS + (SS-1))*HH + e, hv);
}

// ================= persistent decoder =================
struct DecArgs {
  const float *emb;
  const float *bih0d, *bhh0d, *bih1d, *bhh1d, *bq, *bc;
  const float *Wih0P, *Whh0P, *Wih1P, *Whh1P, *WqP, *WcT;
  const float *h0init, *h1init;
  float *dgh0, *dgh1, *h0d, *h1d, *h0n, *h1n, *qbuf;
  float *att, *pm, *pl, *pctx;
  int *tok;
  void *out_enc;
  float *out_vec, *out_attn, *out_hid;
  unsigned *ctr;
};

template<typename ET>
__global__ __launch_bounds__(256) void dec_persist(DecArgs A)
{
  __shared__ float4 smem4[1024];
  float* smem = (float*)smem4;
  __shared__ float lm[4], ll[4];
  __shared__ float s_red[8][33];
  __shared__ int stok[8];
  const int bid = blockIdx.x;
  const int tid = threadIdx.x;
  const int wv = tid >> 6, lane = tid & 63;
  const int grp = bid & 7;
  ET* out_enc = (ET*)A.out_enc;
  unsigned ep = 0;

  for (int t = 0; t < TT; ++t) {
    const int db = t & 1;

    // ---- phase A: cell0 dots ----
    if (bid < 192) {
      const int m = bid / 96, v = bid % 96, rowu = v / 16, bch = v % 16, b0 = bch*8;
      if (m == 1) {
        const float* giB = A.dgh0 + ((size_t)(1-db)*2 + 0)*(size_t)GG*BB;
        const float* ghB = A.dgh0 + ((size_t)(1-db)*2 + 1)*(size_t)GG*BB;
        const float* hpB = A.h0d + (size_t)(1-db)*BB*HH;
        float* hw = A.h0d + (size_t)db*BB*HH;
        for (int u = tid; u < 4*HH; u += 256) {
          int bp = u >> 9, e = u & (HH-1);
          int b = b0 + bp*2;
          float hv0, hv1;
          if (t == 0) {
            hv0 = A.h0init[(size_t)b*HH + e];
            hv1 = A.h0init[(size_t)(b+1)*HH + e];
          } else {
            float2 gir = byp2(&giB[(size_t)e*BB + b]);
            float2 giz = byp2(&giB[(size_t)(HH+e)*BB + b]);
            float2 gin = byp2(&giB[(size_t)(2*HH+e)*BB + b]);
            float2 ghr = byp2(&ghB[(size_t)e*BB + b]);
            float2 ghz = byp2(&ghB[(size_t)(HH+e)*BB + b]);
            float2 ghn = byp2(&ghB[(size_t)(2*HH+e)*BB + b]);
            float bir=A.bih0d[e], biz=A.bih0d[HH+e], bin_=A.bih0d[2*HH+e];
            float bhr=A.bhh0d[e], bhz=A.bhh0d[HH+e], bhn=A.bhh0d[2*HH+e];
            float hp0, hp1;
            if (t == 1) { hp0 = A.h0init[(size_t)b*HH + e]; hp1 = A.h0init[(size_t)(b+1)*HH + e]; }
            else        { hp0 = byp1(&hpB[(size_t)b*HH + e]); hp1 = byp1(&hpB[(size_t)(b+1)*HH + e]); }
            hv0 = gru_out(gir.x+bir, giz.x+biz, gin.x+bin_, ghr.x+bhr, ghz.x+bhz, ghn.x+bhn, hp0);
            hv1 = gru_out(gir.y+bir, giz.y+biz, gin.y+bin_, ghr.y+bhr, ghz.y+bhz, ghn.y+bhn, hp1);
          }
          smem[(bp*2)*HH + e] = hv0;
          smem[(bp*2+1)*HH + e] = hv1;
          if (rowu == 0) {
            hw[(size_t)b*HH + e] = hv0;
            hw[(size_t)(b+1)*HH + e] = hv1;
          }
        }
      } else {
        if (tid < 8) stok[tid] = byp1i(A.tok + b0 + tid);
        __syncthreads();
        for (int u = tid; u < 4*HH; u += 256) {
          int bp = u >> 9, e = u & (HH-1);
          smem[(bp*2)*HH + e]   = A.emb[(size_t)stok[bp*2]*HH + e];
          smem[(bp*2+1)*HH + e] = A.emb[(size_t)stok[bp*2+1]*HH + e];
        }
      }
      __syncthreads();
      const float4* WP = (const float4*)((m == 0) ? A.Wih0P : A.Whh0P);
      const int row = rowu*256 + tid;
      float acc[8] = {0,0,0,0,0,0,0,0};
      dot8p(WP, row, GG, smem4, acc);
      float* dst = A.dgh0 + ((size_t)db*2 + m)*(size_t)GG*BB + (size_t)row*BB + b0;
      *(float4*)dst       = make_float4(acc[0], acc[1], acc[2], acc[3]);
      *(float4*)(dst + 4) = make_float4(acc[4], acc[5], acc[6], acc[7]);
    }
    gbar(A.ctr, grp, 32u, 8u, ep); ep++;

    // ---- phase B: cell1 dots ----
    if (bid < 192) {
      const int m = bid / 96, v = bid % 96, rowu = v / 16, bch = v % 16, b0 = bch*8;
      if (m == 0) {
        const float* giB = A.dgh0 + ((size_t)db*2 + 0)*(size_t)GG*BB;
        const float* ghB = A.dgh0 + ((size_t)db*2 + 1)*(size_t)GG*BB;
        const float* hpB = A.h0d + (size_t)db*BB*HH;
        for (int u = tid; u < 4*HH; u += 256) {
          int bp = u >> 9, e = u & (HH-1);
          int b = b0 + bp*2;
          float2 gir = byp2(&giB[(size_t)e*BB + b]);
          float2 giz = byp2(&giB[(size_t)(HH+e)*BB + b]);
          float2 gin = byp2(&giB[(size_t)(2*HH+e)*BB + b]);
          float2 ghr = byp2(&ghB[(size_t)e*BB + b]);
          float2 ghz = byp2(&ghB[(size_t)(HH+e)*BB + b]);
          float2 ghn = byp2(&ghB[(size_t)(2*HH+e)*BB + b]);
          float bir=A.bih0d[e], biz=A.bih0d[HH+e], bin_=A.bih0d[2*HH+e];
          float bhr=A.bhh0d[e], bhz=A.bhh0d[HH+e], bhn=A.bhh0d[2*HH+e];
          float hp0 = byp1(&hpB[(size_t)b*HH + e]);
          float hp1 = byp1(&hpB[(size_t)(b+1)*HH + e]);
          float hv0 = gru_out(gir.x+bir, giz.x+biz, gin.x+bin_, ghr.x+bhr, ghz.x+bhz, ghn.x+bhn, hp0);
          float hv1 = gru_out(gir.y+bir, giz.y+biz, gin.y+bin_, ghr.y+bhr, ghz.y+bhz, ghn.y+bhn, hp1);
          smem[(bp*2)*HH + e] = hv0;
          smem[(bp*2+1)*HH + e] = hv1;
          if (rowu == 0) {
            A.h0n[(size_t)b*HH + e] = hv0;
            A.h0n[(size_t)(b+1)*HH + e] = hv1;
          }
        }
      } else {
        const float* giB = A.dgh1 + ((size_t)(1-db)*2 + 0)*(size_t)GG*BB;
        const float* ghB = A.dgh1 + ((size_t)(1-db)*2 + 1)*(size_t)GG*BB;
        const float* hpB = A.h1d + (size_t)(1-db)*BB*HH;
        float* hw = A.h1d + (size_t)db*BB*HH;
        for (int u = tid; u < 4*HH; u += 256) {
          int bp = u >> 9, e = u & (HH-1);
          int b = b0 + bp*2;
          float hv0, hv1;
          if (t == 0) {
            hv0 = A.h1init[(size_t)b*HH + e];
            hv1 = A.h1init[(size_t)(b+1)*HH + e];
          } else {
            float2 gir = byp2(&giB[(size_t)e*BB + b]);
            float2 giz = byp2(&giB[(size_t)(HH+e)*BB + b]);
            float2 gin = byp2(&giB[(size_t)(2*HH+e)*BB + b]);
            float2 ghr = byp2(&ghB[(size_t)e*BB + b]);
            float2 ghz = byp2(&ghB[(size_t)(HH+e)*BB + b]);
            float2 ghn = byp2(&ghB[(size_t)(2*HH+e)*BB + b]);
            float bir=A.bih1d[e], biz=A.bih1d[HH+e], bin_=A.bih1d[2*HH+e];
            float bhr=A.bhh1d[e], bhz=A.bhh1d[HH+e], bhn=A.bhh1d[2*HH+e];
            float hp0, hp1;
            if (t == 1) { hp0 = A.h1init[(size_t)b*HH + e]; hp1 = A.h1init[(size_t)(b+1)*HH + e]; }
            else        { hp0 = byp1(&hpB[(size_t)b*HH + e]); hp1 = byp1(&hpB[(size_t)(b+1)*HH + e]); }
            hv0 = gru_out(gir.x+bir, giz.x+biz, gin.x+bin_, ghr.x+bhr, ghz.x+bhz, ghn.x+bhn, hp0);
            hv1 = gru_out(gir.y+bir, giz.y+biz, gin.y+bin_, ghr.y+bhr, ghz.y+bhz, ghn.y+bhn, hp1);
          }
          smem[(bp*2)*HH + e] = hv0;
          smem[(bp*2+1)*HH + e] = hv1;
          if (rowu == 0) {
            hw[(size_t)b*HH + e] = hv0;
            hw[(size_t)(b+1)*HH + e] = hv1;
          }
        }
      }
      __syncthreads();
      const float4* WP = (const float4*)((m == 0) ? A.Wih1P : A.Whh1P);
      const int row = rowu*256 + tid;
      float acc[8] = {0,0,0,0,0,0,0,0};
      dot8p(WP, row, GG, smem4, acc);
      float* dst = A.dgh1 + ((size_t)db*2 + m)*(size_t)GG*BB + (size_t)row*BB + b0;
      *(float4*)dst       = make_float4(acc[0], acc[1], acc[2], acc[3]);
      *(float4*)(dst + 4) = make_float4(acc[4], acc[5], acc[6], acc[7]);
    }
    gbar(A.ctr, grp, 32u, 8u, ep); ep++;

    // ---- phase C: h1n + q ----
    if (bid < 32) {
      const int rowu = bid & 1, bch = bid >> 1, b0 = bch*8;
      const float* giB = A.dgh1 + ((size_t)db*2 + 0)*(size_t)GG*BB;
      const float* ghB = A.dgh1 + ((size_t)db*2 + 1)*(size_t)GG*BB;
      const float* hpB = A.h1d + (size_t)db*BB*HH;
      for (int u = tid; u < 4*HH; u += 256) {
        int bp = u >> 9, e = u & (HH-1);
        int b = b0 + bp*2;
        float2 gir = byp2(&giB[(size_t)e*BB + b]);
        float2 giz = byp2(&giB[(size_t)(HH+e)*BB + b]);
        float2 gin = byp2(&giB[(size_t)(2*HH+e)*BB + b]);
        float2 ghr = byp2(&ghB[(size_t)e*BB + b]);
        float2 ghz = byp2(&ghB[(size_t)(HH+e)*BB + b]);
        float2 ghn = byp2(&ghB[(size_t)(2*HH+e)*BB + b]);
        float bir=A.bih1d[e], biz=A.bih1d[HH+e], bin_=A.bih1d[2*HH+e];
        float bhr=A.bhh1d[e], bhz=A.bhh1d[HH+e], bhn=A.bhh1d[2*HH+e];
        float hp0 = byp1(&hpB[(size_t)b*HH + e]);
        float hp1 = byp1(&hpB[(size_t)(b+1)*HH + e]);
        float hv0 = gru_out(gir.x+bir, giz.x+biz, gin.x+bin_, ghr.x+bhr, ghz.x+bhz, ghn.x+bhn, hp0);
        float hv1 = gru_out(gir.y+bir, giz.y+biz, gin.y+bin_, ghr.y+bhr, ghz.y+bhz, ghn.y+bhn, hp1);
        smem[(bp*2)*HH + e] = hv0;
        smem[(bp*2+1)*HH + e] = hv1;
        if (rowu == 0) {
          A.h1n[(size_t)b*HH + e] = hv0;
          A.h1n[(size_t)(b+1)*HH + e] = hv1;
        }
      }
      __syncthreads();
      const int row = rowu*256 + tid;
      float acc[8] = {0,0,0,0,0,0,0,0};
      dot8p((const float4*)A.WqP, row, HH, smem4, acc);
      float bqv = A.bq[row];
      float* dst = A.qbuf + (size_t)row*BB + b0;
      *(float4*)dst       = make_float4(acc[0]+bqv, acc[1]+bqv, acc[2]+bqv, acc[3]+bqv);
      *(float4*)(dst + 4) = make_float4(acc[4]+bqv, acc[5]+bqv, acc[6]+bqv, acc[7]+bqv);
    }
    gbar(A.ctr, grp, 32u, 8u, ep); ep++;

    // ---- phase D: attention (1024 units, 4 per block) ----
    for (int u = bid; u < BB*8; u += DEC_BLOCKS) {
      const int b = u >> 3, sc = u & 7;
      __syncthreads();
      F8 q;
      #pragma unroll
      for (int jj = 0; jj < 8; jj++)
        q.v[jj] = byp1(&A.qbuf[(size_t)(lane*8 + jj)*BB + b]);
      const ET* encb = out_enc + (size_t)b*SS*HH;
      float mrun = -1e30f, lrun = 0.f;
      float c[8] = {0,0,0,0,0,0,0,0};
      float attkeep = 0.f;
      const int sbase = sc*128 + wv*32;
      for (int ii = 0; ii < 32; ii++) {
        const F8 e = load8(encb + (size_t)(sbase + ii)*HH + lane*8);
        float d = 0.f;
        #pragma unroll
        for (int jj = 0; jj < 8; jj++) d = fmaf(q.v[jj], e.v[jj], d);
        #pragma unroll
        for (int off = 32; off >= 1; off >>= 1) d += __shfl_xor(d, off, 64);
        if (lane == ii) attkeep = d;
        float mnew = fmaxf(mrun, d);
        float scal = fexp(mrun - mnew);
        float pv = fexp(d - mnew);
        lrun = fmaf(lrun, scal, pv);
        #pragma unroll
        for (int jj = 0; jj < 8; jj++) c[jj] = fmaf(c[jj], scal, pv*e.v[jj]);
        mrun = mnew;
      }
      if (lane < 32) A.att[(size_t)b*SS + sbase + lane] = attkeep;
      if (lane == 0) { lm[wv] = mrun; ll[wv] = lrun; }
      #pragma unroll
      for (int jj = 0; jj < 8; jj++) smem[wv*HH + lane*8 + jj] = c[jj];
      __syncthreads();
      float mb = fmaxf(fmaxf(lm[0],lm[1]), fmaxf(lm[2],lm[3]));
      float e0w = fexp(lm[0]-mb), e1w = fexp(lm[1]-mb), e2w = fexp(lm[2]-mb), e3w = fexp(lm[3]-mb);
      if (tid == 0) {
        A.pm[b*8+sc] = mb;
        A.pl[b*8+sc] = e0w*ll[0] + e1w*ll[1] + e2w*ll[2] + e3w*ll[3];
      }
      for (int k2 = tid; k2 < HH; k2 += 256) {
        float s = e0w*smem[0*HH+k2] + e1w*smem[1*HH+k2] + e2w*smem[2*HH+k2] + e3w*smem[3*HH+k2];
        A.pctx[((size_t)b*8 + sc)*HH + k2] = s;
      }
    }
    gbar(A.ctr, grp, 32u, 8u, ep); ep++;

    // ---- phase E: combine + attn-out + logits + argmax ----
    if (bid < BB) {
      const int b = bid;
      float* s_hc = smem;
      float pmv[8], plv[8];
      #pragma unroll
      for (int c8 = 0; c8 < 8; c8++){
        pmv[c8] = byp1(&A.pm[b*8+c8]);
        plv[c8] = byp1(&A.pl[b*8+c8]);
      }
      float mg = pmv[0];
      #pragma unroll
      for (int c8 = 1; c8 < 8; c8++) mg = fmaxf(mg, pmv[c8]);
      float epm[8]; float lg = 0.f;
      #pragma unroll
      for (int c8 = 0; c8 < 8; c8++){ epm[c8] = fexp(pmv[c8]-mg); lg += epm[c8]*plv[c8]; }
      float inv_lg = 1.f/lg;
      {
        int k = tid*2;
        float2 s2 = make_float2(0.f, 0.f);
        #pragma unroll
        for (int c8 = 0; c8 < 8; c8++){
          float2 pc = byp2(&A.pctx[((size_t)b*8+c8)*HH + k]);
          s2.x += epm[c8]*pc.x; s2.y += epm[c8]*pc.y;
        }
        float2 h2 = byp2(&A.h1n[(size_t)b*HH + k]);
        s_hc[HH + k]   = s2.x * inv_lg;
        s_hc[HH + k+1] = s2.y * inv_lg;
        s_hc[k]   = h2.x;
        s_hc[k+1] = h2.y;
      }
      __syncthreads();
      for (int s = tid*2; s < SS; s += 512) {
        float2 av = byp2(&A.att[(size_t)b*SS + s]);
        A.out_attn[((size_t)b*SS + s)*TT + t]     = fexp(av.x - mg) * inv_lg;
        A.out_attn[((size_t)b*SS + s + 1)*TT + t] = fexp(av.y - mg) * inv_lg;
      }
      const int v = tid & 31, part = tid >> 5;
      float pacc = 0.f;
      for (int k = part*128; k < part*128 + 128; k++)
        pacc = fmaf(s_hc[k], A.WcT[(size_t)k*VV + v], pacc);
      s_red[part][v] = pacc;
      __syncthreads();
      if (tid < 32) {
        float lv = A.bc[tid];
        #pragma unroll
        for (int c8 = 0; c8 < 8; c8++) lv += s_red[c8][tid];
        A.out_vec[((size_t)b*TT + t)*VV + tid] = lv;
        float bv = lv; int bi = tid;
        #pragma unroll
        for (int off = 16; off >= 1; off >>= 1) {
          float ov = __shfl_xor(bv, off, 64);
          int   oi = __shfl_xor(bi, off, 64);
          if (ov > bv || (ov == bv && oi < bi)) { bv = ov; bi = oi; }
        }
        if (tid == 0) A.tok[b] = bi;
      }
    }
    gbar(A.ctr, grp, 32u, 8u, ep); ep++;
  }

  for (int i = bid*256 + tid; i < BB*HH; i += DEC_BLOCKS*256) {
    A.out_hid[i] = byp1(&A.h0n[i]);
    A.out_hid[BB*HH + i] = byp1(&A.h1n[i]);
  }
}

// ================= host =================
template<typename ET>
static void launch_all(EncArgs& EA, DecArgs& DA, hipStream_t stream) {
  void* ep[1] = { &EA };
  hipLaunchCooperativeKernel((const void*)&enc_persist<ET>, dim3(ENC_BLOCKS), dim3(192),
                             ep, 0, stream);
  enc_bridge<ET><<<dim3(256), dim3(256), 0, stream>>>(
      EA.gh, EA.h1buf, EA.bih1, EA.bhh1,
      (float*)DA.h1init, (ET*)EA.out_enc);
  void* dp[1] = { &DA };
  hipLaunchCooperativeKernel((const void*)&dec_persist<ET>, dim3(DEC_BLOCKS), dim3(256),
                             dp, 0, stream);
}

extern "C" void kernel_launch(void* const* d_in, const int* in_sizes, int n_in,
                              void* d_out, int out_size, void* d_ws, size_t ws_size,
                              hipStream_t stream) {
  const float* x      = (const float*)d_in[0];
  const float* emb    = (const float*)d_in[1];
  const float* eWih0  = (const float*)d_in[2];
  const float* eWhh0  = (const float*)d_in[3];
  const float* ebih0  = (const float*)d_in[4];
  const float* ebhh0  = (const float*)d_in[5];
  const float* eWih1  = (const float*)d_in[6];
  const float* eWhh1  = (const float*)d_in[7];
  const float* ebih1  = (const float*)d_in[8];
  const float* ebhh1  = (const float*)d_in[9];
  const float* dWih0  = (const float*)d_in[10];
  const float* dWhh0  = (const float*)d_in[11];
  const float* dbih0  = (const float*)d_in[12];
  const float* dbhh0  = (const float*)d_in[13];
  const float* dWih1  = (const float*)d_in[14];
  const float* dWhh1  = (const float*)d_in[15];
  const float* dbih1  = (const float*)d_in[16];
  const float* dbhh1  = (const float*)d_in[17];
  const float* Wq     = (const float*)d_in[18];
  const float* bq     = (const float*)d_in[19];
  const float* Wc     = (const float*)d_in[20];
  const float* bc     = (const float*)d_in[21];
  (void)in_sizes; (void)n_in; (void)out_size;

  float* ws = (float*)d_ws;
  size_t off = 0;
  auto alloc = [&](size_t n){ float* p = ws + off; off += n; return p; };
  const size_t PKB = (size_t)GG*HH + 32*GG;
  const size_t PKQ = (size_t)HH*HH + 32*HH;

  float* gh      = alloc((size_t)2*3*GG*BB);
  float* dgh0    = alloc((size_t)2*2*GG*BB);
  float* dgh1    = alloc((size_t)2*2*GG*BB);
  float* h0buf   = alloc((size_t)2*BB*HH);
  float* h1buf   = alloc((size_t)2*BB*HH);
  float* h0d     = alloc((size_t)2*BB*HH);
  float* h1d     = alloc((size_t)2*BB*HH);
  float* h0n     = alloc((size_t)BB*HH);
  float* h1n     = alloc((size_t)BB*HH);
  float* h1init  = alloc((size_t)BB*HH);
  float* qbuf    = alloc((size_t)HH*BB);
  float* att     = alloc((size_t)BB*SS);
  float* pmb     = alloc((size_t)BB*8);
  float* plb     = alloc((size_t)BB*8);
  float* pctx    = alloc((size_t)BB*8*HH);
  int*   tok     = (int*)alloc((size_t)BB);
  unsigned* ctrs = (unsigned*)alloc((size_t)512);   // enc @0, dec @256
  float* Whh0P   = alloc(PKB);
  float* Wih1P   = alloc(PKB);
  float* Whh1P   = alloc(PKB);
  float* dWih0P  = alloc(PKB);
  float* dWhh0P  = alloc(PKB);
  float* dWih1P  = alloc(PKB);
  float* dWhh1P  = alloc(PKB);
  float* WqP     = alloc(PKQ);
  float* WcT     = alloc((size_t)2*HH*VV);

  float* out_vec  = (float*)d_out;
  float* out_hid  = (float*)d_out + (size_t)BB*TT*VV;
  float* out_attn = (float*)d_out + (size_t)BB*TT*VV + (size_t)2*BB*HH;

  hipMemsetAsync(ctrs, 0, 512*sizeof(unsigned), stream);
  hipMemsetAsync(tok, 0, BB*sizeof(int), stream);

  dim3 tb(256);
  pack_w<<<dim3(GG*HH/256), tb, 0, stream>>>(eWhh0, Whh0P, GG);
  pack_w<<<dim3(GG*HH/256), tb, 0, stream>>>(eWih1, Wih1P, GG);
  pack_w<<<dim3(GG*HH/256), tb, 0, stream>>>(eWhh1, Whh1P, GG);
  pack_w<<<dim3(GG*HH/256), tb, 0, stream>>>(dWih0, dWih0P, GG);
  pack_w<<<dim3(GG*HH/256), tb, 0, stream>>>(dWhh0, dWhh0P, GG);
  pack_w<<<dim3(GG*HH/256), tb, 0, stream>>>(dWih1, dWih1P, GG);
  pack_w<<<dim3(GG*HH/256), tb, 0, stream>>>(dWhh1, dWhh1P, GG);
  pack_w<<<dim3(HH*HH/256), tb, 0, stream>>>(Wq, WqP, HH);
  transpose_k<<<dim3(32,1),  tb, 0, stream>>>(Wc, WcT, VV, 2*HH);

  EncArgs EA;
  EA.x = x; EA.Wih0 = eWih0; EA.bih0 = ebih0; EA.bhh0 = ebhh0;
  EA.bih1 = ebih1; EA.bhh1 = ebhh1;
  EA.Whh0P = Whh0P; EA.Wih1P = Wih1P; EA.Whh1P = Whh1P;
  EA.gh = gh; EA.h0buf = h0buf; EA.h1buf = h1buf;
  EA.ctr = ctrs;

  DecArgs DA;
  DA.emb = emb;
  DA.bih0d = dbih0; DA.bhh0d = dbhh0; DA.bih1d = dbih1; DA.bhh1d = dbhh1;
  DA.bq = bq; DA.bc = bc;
  DA.Wih0P = dWih0P; DA.Whh0P = dWhh0P; DA.Wih1P = dWih1P; DA.Whh1P = dWhh1P;
  DA.WqP = WqP; DA.WcT = WcT;
  DA.h0init = h0buf;           // half 0 = h0 after step 1023
  DA.h1init = h1init;
  DA.dgh0 = dgh0; DA.dgh1 = dgh1; DA.h0d = h0d; DA.h1d = h1d;
  DA.h0n = h0n; DA.h1n = h1n; DA.qbuf = qbuf;
  DA.att = att; DA.pm = pmb; DA.pl = plb; DA.pctx = pctx;
  DA.tok = tok;
  DA.out_vec = out_vec; DA.out_attn = out_attn; DA.out_hid = out_hid;
  DA.ctr = ctrs + 256;

  const size_t enc_elems = (size_t)BB*SS*HH;
  const size_t need32 = (off + enc_elems) * sizeof(float);
  if (ws_size >= need32) {
    float* out_enc = ws + off;
    EA.out_enc = out_enc; DA.out_enc = out_enc;
    launch_all<float>(EA, DA, stream);
  } else {
    __half* out_enc = reinterpret_cast<__half*>(ws + off);
    EA.out_enc = out_enc; DA.out_enc = out_enc;
    launch_all<__half>(EA, DA, stream);
  }
}